// Round 14
// baseline (177.929 us; speedup 1.0000x reference)
//
#include <hip/hip_runtime.h>
#include <hip/hip_bf16.h>

#define HID   256
#define NP    100
#define KSZ   3
#define NPKS  (NP*KSZ)        // 300
#define K2PAD 384             // 3 * 128 (t*128 + c layout)
#define N1T   24              // 384/16 N-tiles of GEMM1
#define PC    104             // kT pitch in bf16 elems (c-dim)
#define KTROWS 258            // l = -1 .. 256
#define KT_ELEMS (KTROWS*PC + 80)   // 26912 shorts = 53824 B (80-short guard for c>104 reads)
#define WS_PITCH 40
#define WS_ELEMS (112*WS_PITCH)

using bf16x8 = __attribute__((ext_vector_type(8))) short;
using f32x4  = __attribute__((ext_vector_type(4))) float;

__device__ __forceinline__ short f2bf(float x) {
    __hip_bfloat16 h = __float2bfloat16(x);
    return __builtin_bit_cast(short, h);
}

// ---------- prep: W_lin -> bf16 B-fragment-ordered W2f, permuted bias ----------
__global__ void dyconv_prep(const float* __restrict__ W_lin,
                            const float* __restrict__ b_lin,
                            short* __restrict__ W2f,   // [8 kt][24 nt][64 lane][8] bf16
                            float* __restrict__ b2f) { // [384]
    int gid = blockIdx.x * blockDim.x + threadIdx.x;   // 0..12287
    int lane = gid & 63;
    int ent  = gid >> 6;            // kt*24 + nt
    int kt = ent / N1T;
    int nt = ent % N1T;
    int n  = nt*16 + (lane & 15);   // K2 index of GEMM2 = t*128 + c
    int t  = n >> 7;
    int c  = n & 127;
    int k0 = kt*32 + ((lane >> 4) << 3);
    short vals[8];
#pragma unroll
    for (int j = 0; j < 8; ++j) {
        float v = (c < NP) ? W_lin[(k0 + j) * NPKS + c*KSZ + t] : 0.0f;
        vals[j] = f2bf(v);
    }
    *reinterpret_cast<bf16x8*>(&W2f[(size_t)gid * 8]) =
        *reinterpret_cast<bf16x8*>(vals);
    if (gid < K2PAD) {
        int tt = gid >> 7, cc = gid & 127;
        b2f[gid] = (cc < NP) ? b_lin[cc*KSZ + tt] : 0.0f;
    }
}

// ---------- kernel A v8: 3-buffer LDS rotation, counted vmcnt(4) (T4) ----------
// 2 chunks of DMA in flight across barriers; bias hoisted so the vmcnt count
// only tracks DMA + (one-iter-old) stores.
__global__ __launch_bounds__(256, 4)
void dyconv_gemm1(const float* __restrict__ f, const short* __restrict__ W2f,
                  const float* __restrict__ b2f, short* __restrict__ w2, int Mrows) {
    __shared__ short wlds[3][16*512];   // 3 x 16KB: 16 frags (ntl*8+kt) x 1KB
    const int tid = threadIdx.x, wave = tid>>6, lane = tid&63, lg = lane>>4, li = lane&15;
    const int r0 = blockIdx.x * 128;

    // bias for all 24 nt hoisted (keeps loop free of stray VMEM loads)
    float biasAll[24];
#pragma unroll
    for (int nt = 0; nt < 24; ++nt) biasAll[nt] = b2f[nt*16 + li];

    // f fragments for 2 M-tiles (64 VGPR), read once
    bf16x8 a1[2][8];
#pragma unroll
    for (int mi = 0; mi < 2; ++mi) {
        int myr = r0 + (wave*2 + mi)*16 + li; if (myr > Mrows-1) myr = Mrows-1;
        const float* frow = f + (size_t)myr * HID + lg*8;
#pragma unroll
        for (int kt = 0; kt < 8; ++kt) {
            float4 u = *reinterpret_cast<const float4*>(frow + kt*32);
            float4 v = *reinterpret_cast<const float4*>(frow + kt*32 + 4);
            short tmp[8] = {f2bf(u.x),f2bf(u.y),f2bf(u.z),f2bf(u.w),
                            f2bf(v.x),f2bf(v.y),f2bf(v.z),f2bf(v.w)};
            a1[mi][kt] = *reinterpret_cast<bf16x8*>(tmp);
        }
    }

    // stage chunk C (nt = C*2, C*2+1) into buffer BUF: wave stages frags wave*4..wave*4+3
#define STAGE(BUF, C) { _Pragma("unroll") for (int i = 0; i < 4; ++i) { \
        int fi = wave*4 + i; \
        int ntl = fi >> 3, kt = fi & 7; \
        int nt = (C)*2 + ntl; \
        const short* gsrc = &W2f[(((size_t)(kt*N1T + nt))*64 + lane)*8]; \
        __builtin_amdgcn_global_load_lds( \
            (const __attribute__((address_space(1))) unsigned int*)gsrc, \
            (__attribute__((address_space(3))) unsigned int*)&wlds[BUF][fi*512], \
            16, 0, 0); } }

    const int prow0 = lg*4;

    STAGE(0, 0)
    STAGE(1, 1)
    asm volatile("s_waitcnt vmcnt(4)" ::: "memory");  // chunk 0 landed (4 newest = chunk 1)
    __syncthreads();

#pragma unroll 1
    for (int c = 0; c < 12; ++c) {
        if (c + 2 < 12) STAGE((c+2)%3, c+2)

        const short* lbase = wlds[c%3];
        f32x4 acc[2][2];
#pragma unroll
        for (int mi = 0; mi < 2; ++mi)
#pragma unroll
            for (int i = 0; i < 2; ++i) acc[mi][i] = (f32x4){0.f,0.f,0.f,0.f};

#pragma unroll
        for (int ntl = 0; ntl < 2; ++ntl) {
#pragma unroll
            for (int kt = 0; kt < 8; ++kt) {
                bf16x8 bfr = *reinterpret_cast<const bf16x8*>(
                    lbase + (ntl*8 + kt)*512 + lane*8);
                acc[0][ntl] = __builtin_amdgcn_mfma_f32_16x16x32_bf16(
                    a1[0][kt], bfr, acc[0][ntl], 0,0,0);
                acc[1][ntl] = __builtin_amdgcn_mfma_f32_16x16x32_bf16(
                    a1[1][kt], bfr, acc[1][ntl], 0,0,0);
            }
        }

        // chunk c+1 must be landed before next iter's consume: allow only the 4
        // newest VMEM ops (chunk c+2's DMAs) to remain outstanding. Stores from
        // iter c-1 are older and drain here too (overlapped with this consume).
        asm volatile("s_waitcnt vmcnt(4)" ::: "memory");
        __syncthreads();

        // stores for chunk c (after barrier; LDS not touched)
#pragma unroll
        for (int mi = 0; mi < 2; ++mi) {
#pragma unroll
            for (int r = 0; r < 4; ++r) {
                int gr = r0 + (wave*2 + mi)*16 + prow0 + r;
                if (gr < Mrows) {
                    int bb = gr / NP, p = gr % NP;
                    short* wrow = w2 + ((size_t)bb*12*NP + p)*32;
#pragma unroll
                    for (int ntl = 0; ntl < 2; ++ntl) {
                        int nt = c*2 + ntl;
                        wrow[(size_t)(nt>>1)*NP*32 + (nt&1)*16 + li] =
                            f2bf(acc[mi][ntl][r] + biasAll[nt]);
                    }
                }
            }
        }
    }
#undef STAGE
}

// ---------- kernel B v4 (reverted; proven 86 us): conv (GEMM2) + LN ----------
__global__ __launch_bounds__(256, 2)
void dyconv_conv(const float* __restrict__ k, const short* __restrict__ w2,
                 const float* __restrict__ gamma, const float* __restrict__ beta,
                 float* __restrict__ out) {
    __shared__ short kT[KT_ELEMS];     // kT[l+1][c] bf16; LN overlay after
    float* lnbuf = reinterpret_cast<float*>(kT);

    const int b = blockIdx.x, tid = threadIdx.x;
    const int wave = tid>>6, lane = tid&63, lg = lane>>4, li = lane&15;

    // zero exactly the never-staged, reachable bytes
    if (tid < 52) {
        *reinterpret_cast<unsigned int*>(&kT[tid*2]) = 0u;
        *reinterpret_cast<unsigned int*>(&kT[257*PC + tid*2]) = 0u;
    }
    *reinterpret_cast<unsigned long long*>(&kT[(tid+1)*PC + 100]) = 0ull;
    if (tid < 20)
        *reinterpret_cast<unsigned long long*>(&kT[KTROWS*PC + tid*4]) = 0ull;

    // staging: 2 channels packed per b32 write; lanes walk l (stride 52 dwords, ~8-way)
    const float* kb = k + (size_t)b * (NP*HID);
    for (int u = tid; u < (NP/2)*HID; u += 256) {   // 12800 units
        int c2 = u >> 8;              // 0..49
        int l  = u & 255;
        int c  = c2*2;
        float v0 = kb[(size_t)c*HID + l];
        float v1 = kb[(size_t)(c+1)*HID + l];
        unsigned int pk = (unsigned int)(unsigned short)f2bf(v0)
                        | ((unsigned int)(unsigned short)f2bf(v1) << 16);
        *reinterpret_cast<unsigned int*>(&kT[(l+1)*PC + c]) = pk;
    }

    f32x4 acc2[7][4];
#pragma unroll
    for (int mt = 0; mt < 7; ++mt)
#pragma unroll
        for (int j = 0; j < 4; ++j) acc2[mt][j] = (f32x4){0.f,0.f,0.f,0.f};

    const short* wb = w2 + (size_t)b * 12 * NP * 32;
    const short* wp[7];
#pragma unroll
    for (int mt = 0; mt < 7; ++mt) {
        int p = mt*16 + li; if (p > NP-1) p = NP-1;
        wp[mt] = wb + (size_t)p*32 + lg*8;
    }

    __syncthreads();   // kT ready; no more barriers until epilogue

    bf16x8 a2[7], a2n[7];
#pragma unroll
    for (int mt = 0; mt < 7; ++mt)
        a2[mt] = *reinterpret_cast<const bf16x8*>(wp[mt]);

#pragma unroll
    for (int kc = 0; kc < 12; ++kc) {
        if (kc < 11) {
#pragma unroll
            for (int mt = 0; mt < 7; ++mt)
                a2n[mt] = *reinterpret_cast<const bf16x8*>(wp[mt] + (size_t)(kc+1)*NP*32);
        }
        int k2 = kc*32 + lg*8;
        int t  = k2 >> 7, c = k2 & 127;
#pragma unroll
        for (int j = 0; j < 4; ++j) {
            int l = (wave*4 + j)*16 + li;
            bf16x8 b2v = *reinterpret_cast<const bf16x8*>(&kT[(l + t)*PC + c]);
#pragma unroll
            for (int mt = 0; mt < 7; ++mt)
                acc2[mt][j] = __builtin_amdgcn_mfma_f32_16x16x32_bf16(
                    a2[mt], b2v, acc2[mt][j], 0,0,0);
        }
#pragma unroll
        for (int mt = 0; mt < 7; ++mt) a2[mt] = a2n[mt];
    }

    __syncthreads();   // kT reads done; overlay LN buffers

    float* psum  = lnbuf;            // [4][112][2]
    float* mrstd = lnbuf + 4*112*2;  // [112][2]
#pragma unroll
    for (int mt = 0; mt < 7; ++mt) {
#pragma unroll
        for (int r = 0; r < 4; ++r) {
            float s1 = 0.f, s2 = 0.f;
#pragma unroll
            for (int j = 0; j < 4; ++j) {
                float v = acc2[mt][j][r];
                s1 += v; s2 += v*v;
            }
#pragma unroll
            for (int m = 1; m < 16; m <<= 1) {
                s1 += __shfl_xor(s1, m, 64);
                s2 += __shfl_xor(s2, m, 64);
            }
            if (li == 0) {
                int p = mt*16 + lg*4 + r;
                psum[(wave*112 + p)*2 + 0] = s1;
                psum[(wave*112 + p)*2 + 1] = s2;
            }
        }
    }
    __syncthreads();
    if (tid < 112) {
        float S1 = 0.f, S2 = 0.f;
#pragma unroll
        for (int w2i = 0; w2i < 4; ++w2i) {
            S1 += psum[(w2i*112 + tid)*2 + 0];
            S2 += psum[(w2i*112 + tid)*2 + 1];
        }
        float mean = S1 * (1.0f/HID);
        float var  = S2 * (1.0f/HID) - mean*mean;
        mrstd[tid*2 + 0] = mean;
        mrstd[tid*2 + 1] = rsqrtf(var + 1e-5f);
    }
    __syncthreads();

    float* ob = out + (size_t)b * (NP*HID);
#pragma unroll
    for (int j = 0; j < 4; ++j) {
        int l = (wave*4 + j)*16 + li;
        float g  = gamma[l];
        float be = beta[l];
#pragma unroll
        for (int mt = 0; mt < 7; ++mt) {
#pragma unroll
            for (int r = 0; r < 4; ++r) {
                int p = mt*16 + lg*4 + r;
                if (p < NP) {
                    float mean = mrstd[p*2], rstd = mrstd[p*2 + 1];
                    ob[p*HID + l] = (acc2[mt][j][r] - mean)*rstd*g + be;
                }
            }
        }
    }
}

// ---------- fallback fused kernel (proven R1 path) if ws too small ----------
__global__ __launch_bounds__(256)
void dyconv_main(const float* __restrict__ f, const float* __restrict__ k,
                 const short* __restrict__ W2f, const float* __restrict__ b2f,
                 const float* __restrict__ gamma, const float* __restrict__ beta,
                 float* __restrict__ out) {
    __shared__ short kT[KT_ELEMS];
    __shared__ short wS[WS_ELEMS];
    float* lnbuf = reinterpret_cast<float*>(wS);
    const int b = blockIdx.x, tid = threadIdx.x;
    const int wave = tid>>6, lane = tid&63, lg = lane>>4, li = lane&15;
    for (int i = tid; i < KT_ELEMS/8; i += 256)
        reinterpret_cast<int4*>(kT)[i] = make_int4(0,0,0,0);
    __syncthreads();
    const float* kb = k + (size_t)b * (NP*HID);
    for (int idx = tid; idx < NP*HID; idx += 256) {
        int c = idx >> 8, l = idx & 255;
        kT[(l+1)*PC + c] = f2bf(kb[idx]);
    }
    const float* fb = f + (size_t)b * (NP*HID);
    const int nmy = (wave < 3) ? 2 : 1;
    bf16x8 a1[2][8];
#pragma unroll
    for (int mi = 0; mi < 2; ++mi) {
        if (mi < nmy) {
            int mt = wave + 4*mi;
            int p  = mt*16 + li; if (p > NP-1) p = NP-1;
            const float* rowp = fb + (size_t)p * HID + lg*8;
#pragma unroll
            for (int kt = 0; kt < 8; ++kt) {
                float4 u = *reinterpret_cast<const float4*>(rowp + kt*32);
                float4 v = *reinterpret_cast<const float4*>(rowp + kt*32 + 4);
                short tmp[8] = {f2bf(u.x),f2bf(u.y),f2bf(u.z),f2bf(u.w),
                                f2bf(v.x),f2bf(v.y),f2bf(v.z),f2bf(v.w)};
                a1[mi][kt] = *reinterpret_cast<bf16x8*>(tmp);
            }
        }
    }
    f32x4 acc2[7][4];
#pragma unroll
    for (int mt = 0; mt < 7; ++mt)
#pragma unroll
        for (int j = 0; j < 4; ++j) acc2[mt][j] = (f32x4){0.f,0.f,0.f,0.f};
    __syncthreads();
    for (int kc = 0; kc < 12; ++kc) {
        f32x4 acc1[2][2];
#pragma unroll
        for (int mi = 0; mi < 2; ++mi)
#pragma unroll
            for (int n = 0; n < 2; ++n) acc1[mi][n] = (f32x4){0.f,0.f,0.f,0.f};
#pragma unroll
        for (int kt = 0; kt < 8; ++kt) {
            bf16x8 b1[2];
#pragma unroll
            for (int ntl = 0; ntl < 2; ++ntl) {
                int NT = kc*2 + ntl;
                b1[ntl] = *reinterpret_cast<const bf16x8*>(
                    &W2f[(((size_t)kt*N1T + NT)*64 + lane)*8]);
            }
#pragma unroll
            for (int mi = 0; mi < 2; ++mi) {
                if (mi < nmy) {
                    acc1[mi][0] = __builtin_amdgcn_mfma_f32_16x16x32_bf16(
                        a1[mi][kt], b1[0], acc1[mi][0], 0,0,0);
                    acc1[mi][1] = __builtin_amdgcn_mfma_f32_16x16x32_bf16(
                        a1[mi][kt], b1[1], acc1[mi][1], 0,0,0);
                }
            }
        }
#pragma unroll
        for (int mi = 0; mi < 2; ++mi) {
            if (mi < nmy) {
                int mt = wave + 4*mi;
#pragma unroll
                for (int ntl = 0; ntl < 2; ++ntl) {
                    int col  = ntl*16 + li;
                    float bias = b2f[kc*32 + col];
#pragma unroll
                    for (int r = 0; r < 4; ++r) {
                        int row = mt*16 + lg*4 + r;
                        wS[row*WS_PITCH + col] = f2bf(acc1[mi][ntl][r] + bias);
                    }
                }
            }
        }
        __syncthreads();
        bf16x8 a2[7];
#pragma unroll
        for (int mt = 0; mt < 7; ++mt)
            a2[mt] = *reinterpret_cast<const bf16x8*>(&wS[(mt*16 + li)*WS_PITCH + lg*8]);
        int k2 = kc*32 + lg*8;
        int t  = k2 >> 7, c = k2 & 127;
#pragma unroll
        for (int j = 0; j < 4; ++j) {
            int l = (wave*4 + j)*16 + li;
            bf16x8 b2v = *reinterpret_cast<const bf16x8*>(&kT[(l + t)*PC + c]);
#pragma unroll
            for (int mt = 0; mt < 7; ++mt)
                acc2[mt][j] = __builtin_amdgcn_mfma_f32_16x16x32_bf16(
                    a2[mt], b2v, acc2[mt][j], 0,0,0);
        }
        __syncthreads();
    }
    float* psum  = lnbuf;
    float* mrstd = lnbuf + 4*112*2;
#pragma unroll
    for (int mt = 0; mt < 7; ++mt) {
#pragma unroll
        for (int r = 0; r < 4; ++r) {
            float s1 = 0.f, s2 = 0.f;
#pragma unroll
            for (int j = 0; j < 4; ++j) {
                float v = acc2[mt][j][r];
                s1 += v; s2 += v*v;
            }
#pragma unroll
            for (int m = 1; m < 16; m <<= 1) {
                s1 += __shfl_xor(s1, m, 64);
                s2 += __shfl_xor(s2, m, 64);
            }
            if (li == 0) {
                int p = mt*16 + lg*4 + r;
                psum[(wave*112 + p)*2 + 0] = s1;
                psum[(wave*112 + p)*2 + 1] = s2;
            }
        }
    }
    __syncthreads();
    if (tid < 112) {
        float S1 = 0.f, S2 = 0.f;
#pragma unroll
        for (int w2i = 0; w2i < 4; ++w2i) {
            S1 += psum[(w2i*112 + tid)*2 + 0];
            S2 += psum[(w2i*112 + tid)*2 + 1];
        }
        float mean = S1 * (1.0f/HID);
        float var  = S2 * (1.0f/HID) - mean*mean;
        mrstd[tid*2 + 0] = mean;
        mrstd[tid*2 + 1] = rsqrtf(var + 1e-5f);
    }
    __syncthreads();
    float* ob = out + (size_t)b * (NP*HID);
#pragma unroll
    for (int j = 0; j < 4; ++j) {
        int l = (wave*4 + j)*16 + li;
        float g  = gamma[l];
        float be = beta[l];
#pragma unroll
        for (int mt = 0; mt < 7; ++mt) {
#pragma unroll
            for (int r = 0; r < 4; ++r) {
                int p = mt*16 + lg*4 + r;
                if (p < NP) {
                    float mean = mrstd[p*2], rstd = mrstd[p*2 + 1];
                    ob[p*HID + l] = (acc2[mt][j][r] - mean)*rstd*g + be;
                }
            }
        }
    }
}

extern "C" void kernel_launch(void* const* d_in, const int* in_sizes, int n_in,
                              void* d_out, int out_size, void* d_ws, size_t ws_size,
                              hipStream_t stream) {
    const float* f     = (const float*)d_in[0];
    const float* k     = (const float*)d_in[1];
    const float* W_lin = (const float*)d_in[2];
    const float* b_lin = (const float*)d_in[3];
    const float* gamma = (const float*)d_in[4];
    const float* beta  = (const float*)d_in[5];
    float* out = (float*)d_out;

    short* W2f = (short*)d_ws;                                   // 196608 B
    float* b2f = (float*)((char*)d_ws + 196608);                 // 1536 B
    const size_t off_w2 = 198144;
    const int B = in_sizes[0] / (NP*HID);
    const int Mrows = B * NP;
    const size_t need = off_w2 + (size_t)B * 12 * NP * 32 * 2;   // ~78.8 MB @ B=1024

    dyconv_prep<<<48, 256, 0, stream>>>(W_lin, b_lin, W2f, b2f);

    if (ws_size >= need) {
        short* w2 = (short*)((char*)d_ws + off_w2);
        dyconv_gemm1<<<(Mrows + 127)/128, 256, 0, stream>>>(f, W2f, b2f, w2, Mrows);
        dyconv_conv<<<B, 256, 0, stream>>>(k, w2, gamma, beta, out);
    } else {
        dyconv_main<<<B, 256, 0, stream>>>(f, k, W2f, b2f, gamma, beta, out);
    }
}

// Round 15
// 176.327 us; speedup vs baseline: 1.0091x; 1.0091x over previous
//
#include <hip/hip_runtime.h>
#include <hip/hip_bf16.h>

#define HID   256
#define NP    100
#define KSZ   3
#define NPKS  (NP*KSZ)        // 300
#define K2PAD 384             // 3 * 128 (t*128 + c layout)
#define N1T   24              // 384/16 N-tiles of GEMM1
#define PC    104             // kT pitch in bf16 elems (c-dim)
#define KTROWS 258            // l = -1 .. 256
#define KT_ELEMS (KTROWS*PC + 80)   // 26912 shorts = 53824 B (80-short guard for c>104 reads)
#define WS_PITCH 40
#define WS_ELEMS (112*WS_PITCH)

using bf16x8 = __attribute__((ext_vector_type(8))) short;
using f32x4  = __attribute__((ext_vector_type(4))) float;

__device__ __forceinline__ short f2bf(float x) {
    __hip_bfloat16 h = __float2bfloat16(x);
    return __builtin_bit_cast(short, h);
}

// ---------- prep: W_lin -> bf16 B-fragment-ordered W2f, permuted bias ----------
__global__ void dyconv_prep(const float* __restrict__ W_lin,
                            const float* __restrict__ b_lin,
                            short* __restrict__ W2f,   // [8 kt][24 nt][64 lane][8] bf16
                            float* __restrict__ b2f) { // [384]
    int gid = blockIdx.x * blockDim.x + threadIdx.x;   // 0..12287
    int lane = gid & 63;
    int ent  = gid >> 6;            // kt*24 + nt
    int kt = ent / N1T;
    int nt = ent % N1T;
    int n  = nt*16 + (lane & 15);   // K2 index of GEMM2 = t*128 + c
    int t  = n >> 7;
    int c  = n & 127;
    int k0 = kt*32 + ((lane >> 4) << 3);
    short vals[8];
#pragma unroll
    for (int j = 0; j < 8; ++j) {
        float v = (c < NP) ? W_lin[(k0 + j) * NPKS + c*KSZ + t] : 0.0f;
        vals[j] = f2bf(v);
    }
    *reinterpret_cast<bf16x8*>(&W2f[(size_t)gid * 8]) =
        *reinterpret_cast<bf16x8*>(vals);
    if (gid < K2PAD) {
        int tt = gid >> 7, cc = gid & 127;
        b2f[gid] = (cc < NP) ? b_lin[cc*KSZ + tt] : 0.0f;
    }
}

// ---------- kernel A v9: 3-buffer LDS rotation, counted vmcnt(4), RAW s_barrier ----------
// __syncthreads() would emit a full vmcnt(0) drain (the v8 bug); raw s_barrier +
// per-wave counted vmcnt keeps 1 chunk of DMA in flight across the barrier.
__global__ __launch_bounds__(256, 4)
void dyconv_gemm1(const float* __restrict__ f, const short* __restrict__ W2f,
                  const float* __restrict__ b2f, short* __restrict__ w2, int Mrows) {
    __shared__ short wlds[3][16*512];   // 3 x 16KB: 16 frags (ntl*8+kt) x 1KB
    const int tid = threadIdx.x, wave = tid>>6, lane = tid&63, lg = lane>>4, li = lane&15;
    const int r0 = blockIdx.x * 128;

    // bias for all 24 nt hoisted (keeps loop free of stray VMEM loads)
    float biasAll[24];
#pragma unroll
    for (int nt = 0; nt < 24; ++nt) biasAll[nt] = b2f[nt*16 + li];

    // f fragments for 2 M-tiles (64 VGPR), read once
    bf16x8 a1[2][8];
#pragma unroll
    for (int mi = 0; mi < 2; ++mi) {
        int myr = r0 + (wave*2 + mi)*16 + li; if (myr > Mrows-1) myr = Mrows-1;
        const float* frow = f + (size_t)myr * HID + lg*8;
#pragma unroll
        for (int kt = 0; kt < 8; ++kt) {
            float4 u = *reinterpret_cast<const float4*>(frow + kt*32);
            float4 v = *reinterpret_cast<const float4*>(frow + kt*32 + 4);
            short tmp[8] = {f2bf(u.x),f2bf(u.y),f2bf(u.z),f2bf(u.w),
                            f2bf(v.x),f2bf(v.y),f2bf(v.z),f2bf(v.w)};
            a1[mi][kt] = *reinterpret_cast<bf16x8*>(tmp);
        }
    }

    // stage chunk C (nt = C*2, C*2+1) into buffer BUF: wave stages frags wave*4..wave*4+3
#define STAGE(BUF, C) { _Pragma("unroll") for (int i = 0; i < 4; ++i) { \
        int fi = wave*4 + i; \
        int ntl = fi >> 3, kt = fi & 7; \
        int nt = (C)*2 + ntl; \
        const short* gsrc = &W2f[(((size_t)(kt*N1T + nt))*64 + lane)*8]; \
        __builtin_amdgcn_global_load_lds( \
            (const __attribute__((address_space(1))) unsigned int*)gsrc, \
            (__attribute__((address_space(3))) unsigned int*)&wlds[BUF][fi*512], \
            16, 0, 0); } }

    const int prow0 = lg*4;

    STAGE(0, 0)
    STAGE(1, 1)
    // drain everything older than chunk1's 4 DMAs (bias, f, chunk0)
    asm volatile("s_waitcnt vmcnt(4)" ::: "memory");
    __builtin_amdgcn_sched_barrier(0);
    __builtin_amdgcn_s_barrier();
    __builtin_amdgcn_sched_barrier(0);

#pragma unroll 1
    for (int c = 0; c < 12; ++c) {
        if (c + 2 < 12) STAGE((c+2)%3, c+2)

        const short* lbase = wlds[c%3];
        f32x4 acc[2][2];
#pragma unroll
        for (int mi = 0; mi < 2; ++mi)
#pragma unroll
            for (int i = 0; i < 2; ++i) acc[mi][i] = (f32x4){0.f,0.f,0.f,0.f};

#pragma unroll
        for (int ntl = 0; ntl < 2; ++ntl) {
#pragma unroll
            for (int kt = 0; kt < 8; ++kt) {
                bf16x8 bfr = *reinterpret_cast<const bf16x8*>(
                    lbase + (ntl*8 + kt)*512 + lane*8);
                acc[0][ntl] = __builtin_amdgcn_mfma_f32_16x16x32_bf16(
                    a1[0][kt], bfr, acc[0][ntl], 0,0,0);
                acc[1][ntl] = __builtin_amdgcn_mfma_f32_16x16x32_bf16(
                    a1[1][kt], bfr, acc[1][ntl], 0,0,0);
            }
        }

        // allow only the 4 newest VMEM (chunk c+2 DMAs) to stay in flight:
        // forces chunk c+1 + stores(c-1) complete; raw barrier (no vmcnt(0) drain).
        asm volatile("s_waitcnt vmcnt(4)" ::: "memory");
        __builtin_amdgcn_sched_barrier(0);
        __builtin_amdgcn_s_barrier();
        __builtin_amdgcn_sched_barrier(0);

        // stores for chunk c (after barrier; LDS untouched; counted at next wait)
#pragma unroll
        for (int mi = 0; mi < 2; ++mi) {
#pragma unroll
            for (int r = 0; r < 4; ++r) {
                int gr = r0 + (wave*2 + mi)*16 + prow0 + r;
                if (gr < Mrows) {
                    int bb = gr / NP, p = gr % NP;
                    short* wrow = w2 + ((size_t)bb*12*NP + p)*32;
#pragma unroll
                    for (int ntl = 0; ntl < 2; ++ntl) {
                        int nt = c*2 + ntl;
                        wrow[(size_t)(nt>>1)*NP*32 + (nt&1)*16 + li] =
                            f2bf(acc[mi][ntl][r] + biasAll[nt]);
                    }
                }
            }
        }
    }
#undef STAGE
}

// ---------- kernel B v4 (frozen; proven 86 us): conv (GEMM2) + LN ----------
__global__ __launch_bounds__(256, 2)
void dyconv_conv(const float* __restrict__ k, const short* __restrict__ w2,
                 const float* __restrict__ gamma, const float* __restrict__ beta,
                 float* __restrict__ out) {
    __shared__ short kT[KT_ELEMS];     // kT[l+1][c] bf16; LN overlay after
    float* lnbuf = reinterpret_cast<float*>(kT);

    const int b = blockIdx.x, tid = threadIdx.x;
    const int wave = tid>>6, lane = tid&63, lg = lane>>4, li = lane&15;

    // zero exactly the never-staged, reachable bytes
    if (tid < 52) {
        *reinterpret_cast<unsigned int*>(&kT[tid*2]) = 0u;
        *reinterpret_cast<unsigned int*>(&kT[257*PC + tid*2]) = 0u;
    }
    *reinterpret_cast<unsigned long long*>(&kT[(tid+1)*PC + 100]) = 0ull;
    if (tid < 20)
        *reinterpret_cast<unsigned long long*>(&kT[KTROWS*PC + tid*4]) = 0ull;

    // staging: 2 channels packed per b32 write; lanes walk l (stride 52 dwords, ~8-way)
    const float* kb = k + (size_t)b * (NP*HID);
    for (int u = tid; u < (NP/2)*HID; u += 256) {   // 12800 units
        int c2 = u >> 8;              // 0..49
        int l  = u & 255;
        int c  = c2*2;
        float v0 = kb[(size_t)c*HID + l];
        float v1 = kb[(size_t)(c+1)*HID + l];
        unsigned int pk = (unsigned int)(unsigned short)f2bf(v0)
                        | ((unsigned int)(unsigned short)f2bf(v1) << 16);
        *reinterpret_cast<unsigned int*>(&kT[(l+1)*PC + c]) = pk;
    }

    f32x4 acc2[7][4];
#pragma unroll
    for (int mt = 0; mt < 7; ++mt)
#pragma unroll
        for (int j = 0; j < 4; ++j) acc2[mt][j] = (f32x4){0.f,0.f,0.f,0.f};

    const short* wb = w2 + (size_t)b * 12 * NP * 32;
    const short* wp[7];
#pragma unroll
    for (int mt = 0; mt < 7; ++mt) {
        int p = mt*16 + li; if (p > NP-1) p = NP-1;
        wp[mt] = wb + (size_t)p*32 + lg*8;
    }

    __syncthreads();   // kT ready; no more barriers until epilogue

    bf16x8 a2[7], a2n[7];
#pragma unroll
    for (int mt = 0; mt < 7; ++mt)
        a2[mt] = *reinterpret_cast<const bf16x8*>(wp[mt]);

#pragma unroll
    for (int kc = 0; kc < 12; ++kc) {
        if (kc < 11) {
#pragma unroll
            for (int mt = 0; mt < 7; ++mt)
                a2n[mt] = *reinterpret_cast<const bf16x8*>(wp[mt] + (size_t)(kc+1)*NP*32);
        }
        int k2 = kc*32 + lg*8;
        int t  = k2 >> 7, c = k2 & 127;
#pragma unroll
        for (int j = 0; j < 4; ++j) {
            int l = (wave*4 + j)*16 + li;
            bf16x8 b2v = *reinterpret_cast<const bf16x8*>(&kT[(l + t)*PC + c]);
#pragma unroll
            for (int mt = 0; mt < 7; ++mt)
                acc2[mt][j] = __builtin_amdgcn_mfma_f32_16x16x32_bf16(
                    a2[mt], b2v, acc2[mt][j], 0,0,0);
        }
#pragma unroll
        for (int mt = 0; mt < 7; ++mt) a2[mt] = a2n[mt];
    }

    __syncthreads();   // kT reads done; overlay LN buffers

    float* psum  = lnbuf;            // [4][112][2]
    float* mrstd = lnbuf + 4*112*2;  // [112][2]
#pragma unroll
    for (int mt = 0; mt < 7; ++mt) {
#pragma unroll
        for (int r = 0; r < 4; ++r) {
            float s1 = 0.f, s2 = 0.f;
#pragma unroll
            for (int j = 0; j < 4; ++j) {
                float v = acc2[mt][j][r];
                s1 += v; s2 += v*v;
            }
#pragma unroll
            for (int m = 1; m < 16; m <<= 1) {
                s1 += __shfl_xor(s1, m, 64);
                s2 += __shfl_xor(s2, m, 64);
            }
            if (li == 0) {
                int p = mt*16 + lg*4 + r;
                psum[(wave*112 + p)*2 + 0] = s1;
                psum[(wave*112 + p)*2 + 1] = s2;
            }
        }
    }
    __syncthreads();
    if (tid < 112) {
        float S1 = 0.f, S2 = 0.f;
#pragma unroll
        for (int w2i = 0; w2i < 4; ++w2i) {
            S1 += psum[(w2i*112 + tid)*2 + 0];
            S2 += psum[(w2i*112 + tid)*2 + 1];
        }
        float mean = S1 * (1.0f/HID);
        float var  = S2 * (1.0f/HID) - mean*mean;
        mrstd[tid*2 + 0] = mean;
        mrstd[tid*2 + 1] = rsqrtf(var + 1e-5f);
    }
    __syncthreads();

    float* ob = out + (size_t)b * (NP*HID);
#pragma unroll
    for (int j = 0; j < 4; ++j) {
        int l = (wave*4 + j)*16 + li;
        float g  = gamma[l];
        float be = beta[l];
#pragma unroll
        for (int mt = 0; mt < 7; ++mt) {
#pragma unroll
            for (int r = 0; r < 4; ++r) {
                int p = mt*16 + lg*4 + r;
                if (p < NP) {
                    float mean = mrstd[p*2], rstd = mrstd[p*2 + 1];
                    ob[p*HID + l] = (acc2[mt][j][r] - mean)*rstd*g + be;
                }
            }
        }
    }
}

// ---------- fallback fused kernel (proven R1 path) if ws too small ----------
__global__ __launch_bounds__(256)
void dyconv_main(const float* __restrict__ f, const float* __restrict__ k,
                 const short* __restrict__ W2f, const float* __restrict__ b2f,
                 const float* __restrict__ gamma, const float* __restrict__ beta,
                 float* __restrict__ out) {
    __shared__ short kT[KT_ELEMS];
    __shared__ short wS[WS_ELEMS];
    float* lnbuf = reinterpret_cast<float*>(wS);
    const int b = blockIdx.x, tid = threadIdx.x;
    const int wave = tid>>6, lane = tid&63, lg = lane>>4, li = lane&15;
    for (int i = tid; i < KT_ELEMS/8; i += 256)
        reinterpret_cast<int4*>(kT)[i] = make_int4(0,0,0,0);
    __syncthreads();
    const float* kb = k + (size_t)b * (NP*HID);
    for (int idx = tid; idx < NP*HID; idx += 256) {
        int c = idx >> 8, l = idx & 255;
        kT[(l+1)*PC + c] = f2bf(kb[idx]);
    }
    const float* fb = f + (size_t)b * (NP*HID);
    const int nmy = (wave < 3) ? 2 : 1;
    bf16x8 a1[2][8];
#pragma unroll
    for (int mi = 0; mi < 2; ++mi) {
        if (mi < nmy) {
            int mt = wave + 4*mi;
            int p  = mt*16 + li; if (p > NP-1) p = NP-1;
            const float* rowp = fb + (size_t)p * HID + lg*8;
#pragma unroll
            for (int kt = 0; kt < 8; ++kt) {
                float4 u = *reinterpret_cast<const float4*>(rowp + kt*32);
                float4 v = *reinterpret_cast<const float4*>(rowp + kt*32 + 4);
                short tmp[8] = {f2bf(u.x),f2bf(u.y),f2bf(u.z),f2bf(u.w),
                                f2bf(v.x),f2bf(v.y),f2bf(v.z),f2bf(v.w)};
                a1[mi][kt] = *reinterpret_cast<bf16x8*>(tmp);
            }
        }
    }
    f32x4 acc2[7][4];
#pragma unroll
    for (int mt = 0; mt < 7; ++mt)
#pragma unroll
        for (int j = 0; j < 4; ++j) acc2[mt][j] = (f32x4){0.f,0.f,0.f,0.f};
    __syncthreads();
    for (int kc = 0; kc < 12; ++kc) {
        f32x4 acc1[2][2];
#pragma unroll
        for (int mi = 0; mi < 2; ++mi)
#pragma unroll
            for (int n = 0; n < 2; ++n) acc1[mi][n] = (f32x4){0.f,0.f,0.f,0.f};
#pragma unroll
        for (int kt = 0; kt < 8; ++kt) {
            bf16x8 b1[2];
#pragma unroll
            for (int ntl = 0; ntl < 2; ++ntl) {
                int NT = kc*2 + ntl;
                b1[ntl] = *reinterpret_cast<const bf16x8*>(
                    &W2f[(((size_t)kt*N1T + NT)*64 + lane)*8]);
            }
#pragma unroll
            for (int mi = 0; mi < 2; ++mi) {
                if (mi < nmy) {
                    acc1[mi][0] = __builtin_amdgcn_mfma_f32_16x16x32_bf16(
                        a1[mi][kt], b1[0], acc1[mi][0], 0,0,0);
                    acc1[mi][1] = __builtin_amdgcn_mfma_f32_16x16x32_bf16(
                        a1[mi][kt], b1[1], acc1[mi][1], 0,0,0);
                }
            }
        }
#pragma unroll
        for (int mi = 0; mi < 2; ++mi) {
            if (mi < nmy) {
                int mt = wave + 4*mi;
#pragma unroll
                for (int ntl = 0; ntl < 2; ++ntl) {
                    int col  = ntl*16 + li;
                    float bias = b2f[kc*32 + col];
#pragma unroll
                    for (int r = 0; r < 4; ++r) {
                        int row = mt*16 + lg*4 + r;
                        wS[row*WS_PITCH + col] = f2bf(acc1[mi][ntl][r] + bias);
                    }
                }
            }
        }
        __syncthreads();
        bf16x8 a2[7];
#pragma unroll
        for (int mt = 0; mt < 7; ++mt)
            a2[mt] = *reinterpret_cast<const bf16x8*>(&wS[(mt*16 + li)*WS_PITCH + lg*8]);
        int k2 = kc*32 + lg*8;
        int t  = k2 >> 7, c = k2 & 127;
#pragma unroll
        for (int j = 0; j < 4; ++j) {
            int l = (wave*4 + j)*16 + li;
            bf16x8 b2v = *reinterpret_cast<const bf16x8*>(&kT[(l + t)*PC + c]);
#pragma unroll
            for (int mt = 0; mt < 7; ++mt)
                acc2[mt][j] = __builtin_amdgcn_mfma_f32_16x16x32_bf16(
                    a2[mt], b2v, acc2[mt][j], 0,0,0);
        }
        __syncthreads();
    }
    float* psum  = lnbuf;
    float* mrstd = lnbuf + 4*112*2;
#pragma unroll
    for (int mt = 0; mt < 7; ++mt) {
#pragma unroll
        for (int r = 0; r < 4; ++r) {
            float s1 = 0.f, s2 = 0.f;
#pragma unroll
            for (int j = 0; j < 4; ++j) {
                float v = acc2[mt][j][r];
                s1 += v; s2 += v*v;
            }
#pragma unroll
            for (int m = 1; m < 16; m <<= 1) {
                s1 += __shfl_xor(s1, m, 64);
                s2 += __shfl_xor(s2, m, 64);
            }
            if (li == 0) {
                int p = mt*16 + lg*4 + r;
                psum[(wave*112 + p)*2 + 0] = s1;
                psum[(wave*112 + p)*2 + 1] = s2;
            }
        }
    }
    __syncthreads();
    if (tid < 112) {
        float S1 = 0.f, S2 = 0.f;
#pragma unroll
        for (int w2i = 0; w2i < 4; ++w2i) {
            S1 += psum[(w2i*112 + tid)*2 + 0];
            S2 += psum[(w2i*112 + tid)*2 + 1];
        }
        float mean = S1 * (1.0f/HID);
        float var  = S2 * (1.0f/HID) - mean*mean;
        mrstd[tid*2 + 0] = mean;
        mrstd[tid*2 + 1] = rsqrtf(var + 1e-5f);
    }
    __syncthreads();
    float* ob = out + (size_t)b * (NP*HID);
#pragma unroll
    for (int j = 0; j < 4; ++j) {
        int l = (wave*4 + j)*16 + li;
        float g  = gamma[l];
        float be = beta[l];
#pragma unroll
        for (int mt = 0; mt < 7; ++mt) {
#pragma unroll
            for (int r = 0; r < 4; ++r) {
                int p = mt*16 + lg*4 + r;
                if (p < NP) {
                    float mean = mrstd[p*2], rstd = mrstd[p*2 + 1];
                    ob[p*HID + l] = (acc2[mt][j][r] - mean)*rstd*g + be;
                }
            }
        }
    }
}

extern "C" void kernel_launch(void* const* d_in, const int* in_sizes, int n_in,
                              void* d_out, int out_size, void* d_ws, size_t ws_size,
                              hipStream_t stream) {
    const float* f     = (const float*)d_in[0];
    const float* k     = (const float*)d_in[1];
    const float* W_lin = (const float*)d_in[2];
    const float* b_lin = (const float*)d_in[3];
    const float* gamma = (const float*)d_in[4];
    const float* beta  = (const float*)d_in[5];
    float* out = (float*)d_out;

    short* W2f = (short*)d_ws;                                   // 196608 B
    float* b2f = (float*)((char*)d_ws + 196608);                 // 1536 B
    const size_t off_w2 = 198144;
    const int B = in_sizes[0] / (NP*HID);
    const int Mrows = B * NP;
    const size_t need = off_w2 + (size_t)B * 12 * NP * 32 * 2;   // ~78.8 MB @ B=1024

    dyconv_prep<<<48, 256, 0, stream>>>(W_lin, b_lin, W2f, b2f);

    if (ws_size >= need) {
        short* w2 = (short*)((char*)d_ws + off_w2);
        dyconv_gemm1<<<(Mrows + 127)/128, 256, 0, stream>>>(f, W2f, b2f, w2, Mrows);
        dyconv_conv<<<B, 256, 0, stream>>>(k, w2, gamma, beta, out);
    } else {
        dyconv_main<<<B, 256, 0, stream>>>(f, k, W2f, b2f, gamma, beta, out);
    }
}

// Round 16
// 149.428 us; speedup vs baseline: 1.1907x; 1.1800x over previous
//
#include <hip/hip_runtime.h>
#include <hip/hip_bf16.h>

#define HID   256
#define NP    100
#define KSZ   3
#define NPKS  (NP*KSZ)        // 300
#define K2PAD 384             // 3 * 128 (t*128 + c layout)
#define N1T   24              // 384/16 N-tiles of GEMM1
#define PC    104             // kT pitch in bf16 elems (c-dim)
#define KTROWS 258            // l = -1 .. 256
#define KT_ELEMS (KTROWS*PC + 80)   // 26912 shorts = 53824 B (80-short guard for c>104 reads)
#define WS_PITCH 40
#define WS_ELEMS (112*WS_PITCH)

using bf16x8 = __attribute__((ext_vector_type(8))) short;
using f32x4  = __attribute__((ext_vector_type(4))) float;

__device__ __forceinline__ short f2bf(float x) {
    __hip_bfloat16 h = __float2bfloat16(x);
    return __builtin_bit_cast(short, h);
}

// ---------- prep: W_lin -> bf16 B-fragment-ordered W2f, permuted bias ----------
__global__ void dyconv_prep(const float* __restrict__ W_lin,
                            const float* __restrict__ b_lin,
                            short* __restrict__ W2f,   // [8 kt][24 nt][64 lane][8] bf16
                            float* __restrict__ b2f) { // [384]
    int gid = blockIdx.x * blockDim.x + threadIdx.x;   // 0..12287
    int lane = gid & 63;
    int ent  = gid >> 6;            // kt*24 + nt
    int kt = ent / N1T;
    int nt = ent % N1T;
    int n  = nt*16 + (lane & 15);   // K2 index of GEMM2 = t*128 + c
    int t  = n >> 7;
    int c  = n & 127;
    int k0 = kt*32 + ((lane >> 4) << 3);
    short vals[8];
#pragma unroll
    for (int j = 0; j < 8; ++j) {
        float v = (c < NP) ? W_lin[(k0 + j) * NPKS + c*KSZ + t] : 0.0f;
        vals[j] = f2bf(v);
    }
    *reinterpret_cast<bf16x8*>(&W2f[(size_t)gid * 8]) =
        *reinterpret_cast<bf16x8*>(vals);
    if (gid < K2PAD) {
        int tt = gid >> 7, cc = gid & 127;
        b2f[gid] = (cc < NP) ? b_lin[cc*KSZ + tt] : 0.0f;
    }
}

// ---------- kernel A v7 (proven ~57us): 2-nt DMA chunks (2x16KB LDS), launch_bounds(256,4) ----------
__global__ __launch_bounds__(256, 4)
void dyconv_gemm1(const float* __restrict__ f, const short* __restrict__ W2f,
                  const float* __restrict__ b2f, short* __restrict__ w2, int Mrows) {
    __shared__ short wlds[2][16*512];   // 2 x 16KB: 16 frags (ntl*8+kt) x 1KB
    const int tid = threadIdx.x, wave = tid>>6, lane = tid&63, lg = lane>>4, li = lane&15;
    const int r0 = blockIdx.x * 128;

    // f fragments for 2 M-tiles (64 VGPR), read once
    bf16x8 a1[2][8];
#pragma unroll
    for (int mi = 0; mi < 2; ++mi) {
        int myr = r0 + (wave*2 + mi)*16 + li; if (myr > Mrows-1) myr = Mrows-1;
        const float* frow = f + (size_t)myr * HID + lg*8;
#pragma unroll
        for (int kt = 0; kt < 8; ++kt) {
            float4 u = *reinterpret_cast<const float4*>(frow + kt*32);
            float4 v = *reinterpret_cast<const float4*>(frow + kt*32 + 4);
            short tmp[8] = {f2bf(u.x),f2bf(u.y),f2bf(u.z),f2bf(u.w),
                            f2bf(v.x),f2bf(v.y),f2bf(v.z),f2bf(v.w)};
            a1[mi][kt] = *reinterpret_cast<bf16x8*>(tmp);
        }
    }

    // stage chunk C (nt = C*2, C*2+1): wave stages frags wave*4 .. wave*4+3
#define STAGE(BUF, C) { _Pragma("unroll") for (int i = 0; i < 4; ++i) { \
        int fi = wave*4 + i; \
        int ntl = fi >> 3, kt = fi & 7; \
        int nt = (C)*2 + ntl; \
        const short* gsrc = &W2f[(((size_t)(kt*N1T + nt))*64 + lane)*8]; \
        __builtin_amdgcn_global_load_lds( \
            (const __attribute__((address_space(1))) unsigned int*)gsrc, \
            (__attribute__((address_space(3))) unsigned int*)&wlds[BUF][fi*512], \
            16, 0, 0); } }

    const int prow0 = lg*4;

    STAGE(0, 0)
    __syncthreads();   // chunk 0 staged (drains f loads too)

#pragma unroll 1
    for (int c = 0; c < 12; ++c) {
        if (c < 11) STAGE((c+1)&1, c+1)

        const short* lbase = wlds[c&1];
        f32x4 acc[2][2];
#pragma unroll
        for (int mi = 0; mi < 2; ++mi)
#pragma unroll
            for (int i = 0; i < 2; ++i) acc[mi][i] = (f32x4){0.f,0.f,0.f,0.f};

#pragma unroll
        for (int ntl = 0; ntl < 2; ++ntl) {
#pragma unroll
            for (int kt = 0; kt < 8; ++kt) {
                bf16x8 bfr = *reinterpret_cast<const bf16x8*>(
                    lbase + (ntl*8 + kt)*512 + lane*8);
                acc[0][ntl] = __builtin_amdgcn_mfma_f32_16x16x32_bf16(
                    a1[0][kt], bfr, acc[0][ntl], 0,0,0);
                acc[1][ntl] = __builtin_amdgcn_mfma_f32_16x16x32_bf16(
                    a1[1][kt], bfr, acc[1][ntl], 0,0,0);
            }
        }

        float bias[2];
#pragma unroll
        for (int ntl = 0; ntl < 2; ++ntl) bias[ntl] = b2f[(c*2 + ntl)*16 + li];

#pragma unroll
        for (int mi = 0; mi < 2; ++mi) {
#pragma unroll
            for (int r = 0; r < 4; ++r) {
                int gr = r0 + (wave*2 + mi)*16 + prow0 + r;
                if (gr < Mrows) {
                    int bb = gr / NP, p = gr % NP;
                    short* wrow = w2 + ((size_t)bb*12*NP + p)*32;
#pragma unroll
                    for (int ntl = 0; ntl < 2; ++ntl) {
                        int nt = c*2 + ntl;
                        wrow[(size_t)(nt>>1)*NP*32 + (nt&1)*16 + li] =
                            f2bf(acc[mi][ntl][r] + bias[ntl]);
                    }
                }
            }
        }
        __syncthreads();   // drains next-chunk DMA + protects buffer swap
    }
#undef STAGE
}

// ---------- kernel B v4 (proven 86 us): conv (GEMM2) + LN ----------
__global__ __launch_bounds__(256, 2)
void dyconv_conv(const float* __restrict__ k, const short* __restrict__ w2,
                 const float* __restrict__ gamma, const float* __restrict__ beta,
                 float* __restrict__ out) {
    __shared__ short kT[KT_ELEMS];     // kT[l+1][c] bf16; LN overlay after
    float* lnbuf = reinterpret_cast<float*>(kT);

    const int b = blockIdx.x, tid = threadIdx.x;
    const int wave = tid>>6, lane = tid&63, lg = lane>>4, li = lane&15;

    // zero exactly the never-staged, reachable bytes
    if (tid < 52) {
        *reinterpret_cast<unsigned int*>(&kT[tid*2]) = 0u;
        *reinterpret_cast<unsigned int*>(&kT[257*PC + tid*2]) = 0u;
    }
    *reinterpret_cast<unsigned long long*>(&kT[(tid+1)*PC + 100]) = 0ull;
    if (tid < 20)
        *reinterpret_cast<unsigned long long*>(&kT[KTROWS*PC + tid*4]) = 0ull;

    // staging: 2 channels packed per b32 write; lanes walk l (stride 52 dwords, ~8-way)
    const float* kb = k + (size_t)b * (NP*HID);
    for (int u = tid; u < (NP/2)*HID; u += 256) {   // 12800 units
        int c2 = u >> 8;              // 0..49
        int l  = u & 255;
        int c  = c2*2;
        float v0 = kb[(size_t)c*HID + l];
        float v1 = kb[(size_t)(c+1)*HID + l];
        unsigned int pk = (unsigned int)(unsigned short)f2bf(v0)
                        | ((unsigned int)(unsigned short)f2bf(v1) << 16);
        *reinterpret_cast<unsigned int*>(&kT[(l+1)*PC + c]) = pk;
    }

    f32x4 acc2[7][4];
#pragma unroll
    for (int mt = 0; mt < 7; ++mt)
#pragma unroll
        for (int j = 0; j < 4; ++j) acc2[mt][j] = (f32x4){0.f,0.f,0.f,0.f};

    const short* wb = w2 + (size_t)b * 12 * NP * 32;
    const short* wp[7];
#pragma unroll
    for (int mt = 0; mt < 7; ++mt) {
        int p = mt*16 + li; if (p > NP-1) p = NP-1;
        wp[mt] = wb + (size_t)p*32 + lg*8;
    }

    __syncthreads();   // kT ready; no more barriers until epilogue

    bf16x8 a2[7], a2n[7];
#pragma unroll
    for (int mt = 0; mt < 7; ++mt)
        a2[mt] = *reinterpret_cast<const bf16x8*>(wp[mt]);

#pragma unroll
    for (int kc = 0; kc < 12; ++kc) {
        if (kc < 11) {
#pragma unroll
            for (int mt = 0; mt < 7; ++mt)
                a2n[mt] = *reinterpret_cast<const bf16x8*>(wp[mt] + (size_t)(kc+1)*NP*32);
        }
        int k2 = kc*32 + lg*8;
        int t  = k2 >> 7, c = k2 & 127;
#pragma unroll
        for (int j = 0; j < 4; ++j) {
            int l = (wave*4 + j)*16 + li;
            bf16x8 b2v = *reinterpret_cast<const bf16x8*>(&kT[(l + t)*PC + c]);
#pragma unroll
            for (int mt = 0; mt < 7; ++mt)
                acc2[mt][j] = __builtin_amdgcn_mfma_f32_16x16x32_bf16(
                    a2[mt], b2v, acc2[mt][j], 0,0,0);
        }
#pragma unroll
        for (int mt = 0; mt < 7; ++mt) a2[mt] = a2n[mt];
    }

    __syncthreads();   // kT reads done; overlay LN buffers

    float* psum  = lnbuf;            // [4][112][2]
    float* mrstd = lnbuf + 4*112*2;  // [112][2]
#pragma unroll
    for (int mt = 0; mt < 7; ++mt) {
#pragma unroll
        for (int r = 0; r < 4; ++r) {
            float s1 = 0.f, s2 = 0.f;
#pragma unroll
            for (int j = 0; j < 4; ++j) {
                float v = acc2[mt][j][r];
                s1 += v; s2 += v*v;
            }
#pragma unroll
            for (int m = 1; m < 16; m <<= 1) {
                s1 += __shfl_xor(s1, m, 64);
                s2 += __shfl_xor(s2, m, 64);
            }
            if (li == 0) {
                int p = mt*16 + lg*4 + r;
                psum[(wave*112 + p)*2 + 0] = s1;
                psum[(wave*112 + p)*2 + 1] = s2;
            }
        }
    }
    __syncthreads();
    if (tid < 112) {
        float S1 = 0.f, S2 = 0.f;
#pragma unroll
        for (int w2i = 0; w2i < 4; ++w2i) {
            S1 += psum[(w2i*112 + tid)*2 + 0];
            S2 += psum[(w2i*112 + tid)*2 + 1];
        }
        float mean = S1 * (1.0f/HID);
        float var  = S2 * (1.0f/HID) - mean*mean;
        mrstd[tid*2 + 0] = mean;
        mrstd[tid*2 + 1] = rsqrtf(var + 1e-5f);
    }
    __syncthreads();

    float* ob = out + (size_t)b * (NP*HID);
#pragma unroll
    for (int j = 0; j < 4; ++j) {
        int l = (wave*4 + j)*16 + li;
        float g  = gamma[l];
        float be = beta[l];
#pragma unroll
        for (int mt = 0; mt < 7; ++mt) {
#pragma unroll
            for (int r = 0; r < 4; ++r) {
                int p = mt*16 + lg*4 + r;
                if (p < NP) {
                    float mean = mrstd[p*2], rstd = mrstd[p*2 + 1];
                    ob[p*HID + l] = (acc2[mt][j][r] - mean)*rstd*g + be;
                }
            }
        }
    }
}

// ---------- fallback fused kernel (proven R1 path) if ws too small ----------
__global__ __launch_bounds__(256)
void dyconv_main(const float* __restrict__ f, const float* __restrict__ k,
                 const short* __restrict__ W2f, const float* __restrict__ b2f,
                 const float* __restrict__ gamma, const float* __restrict__ beta,
                 float* __restrict__ out) {
    __shared__ short kT[KT_ELEMS];
    __shared__ short wS[WS_ELEMS];
    float* lnbuf = reinterpret_cast<float*>(wS);
    const int b = blockIdx.x, tid = threadIdx.x;
    const int wave = tid>>6, lane = tid&63, lg = lane>>4, li = lane&15;
    for (int i = tid; i < KT_ELEMS/8; i += 256)
        reinterpret_cast<int4*>(kT)[i] = make_int4(0,0,0,0);
    __syncthreads();
    const float* kb = k + (size_t)b * (NP*HID);
    for (int idx = tid; idx < NP*HID; idx += 256) {
        int c = idx >> 8, l = idx & 255;
        kT[(l+1)*PC + c] = f2bf(kb[idx]);
    }
    const float* fb = f + (size_t)b * (NP*HID);
    const int nmy = (wave < 3) ? 2 : 1;
    bf16x8 a1[2][8];
#pragma unroll
    for (int mi = 0; mi < 2; ++mi) {
        if (mi < nmy) {
            int mt = wave + 4*mi;
            int p  = mt*16 + li; if (p > NP-1) p = NP-1;
            const float* rowp = fb + (size_t)p * HID + lg*8;
#pragma unroll
            for (int kt = 0; kt < 8; ++kt) {
                float4 u = *reinterpret_cast<const float4*>(rowp + kt*32);
                float4 v = *reinterpret_cast<const float4*>(rowp + kt*32 + 4);
                short tmp[8] = {f2bf(u.x),f2bf(u.y),f2bf(u.z),f2bf(u.w),
                                f2bf(v.x),f2bf(v.y),f2bf(v.z),f2bf(v.w)};
                a1[mi][kt] = *reinterpret_cast<bf16x8*>(tmp);
            }
        }
    }
    f32x4 acc2[7][4];
#pragma unroll
    for (int mt = 0; mt < 7; ++mt)
#pragma unroll
        for (int j = 0; j < 4; ++j) acc2[mt][j] = (f32x4){0.f,0.f,0.f,0.f};
    __syncthreads();
    for (int kc = 0; kc < 12; ++kc) {
        f32x4 acc1[2][2];
#pragma unroll
        for (int mi = 0; mi < 2; ++mi)
#pragma unroll
            for (int n = 0; n < 2; ++n) acc1[mi][n] = (f32x4){0.f,0.f,0.f,0.f};
#pragma unroll
        for (int kt = 0; kt < 8; ++kt) {
            bf16x8 b1[2];
#pragma unroll
            for (int ntl = 0; ntl < 2; ++ntl) {
                int NT = kc*2 + ntl;
                b1[ntl] = *reinterpret_cast<const bf16x8*>(
                    &W2f[(((size_t)kt*N1T + NT)*64 + lane)*8]);
            }
#pragma unroll
            for (int mi = 0; mi < 2; ++mi) {
                if (mi < nmy) {
                    acc1[mi][0] = __builtin_amdgcn_mfma_f32_16x16x32_bf16(
                        a1[mi][kt], b1[0], acc1[mi][0], 0,0,0);
                    acc1[mi][1] = __builtin_amdgcn_mfma_f32_16x16x32_bf16(
                        a1[mi][kt], b1[1], acc1[mi][1], 0,0,0);
                }
            }
        }
#pragma unroll
        for (int mi = 0; mi < 2; ++mi) {
            if (mi < nmy) {
                int mt = wave + 4*mi;
#pragma unroll
                for (int ntl = 0; ntl < 2; ++ntl) {
                    int col  = ntl*16 + li;
                    float bias = b2f[kc*32 + col];
#pragma unroll
                    for (int r = 0; r < 4; ++r) {
                        int row = mt*16 + lg*4 + r;
                        wS[row*WS_PITCH + col] = f2bf(acc1[mi][ntl][r] + bias);
                    }
                }
            }
        }
        __syncthreads();
        bf16x8 a2[7];
#pragma unroll
        for (int mt = 0; mt < 7; ++mt)
            a2[mt] = *reinterpret_cast<const bf16x8*>(&wS[(mt*16 + li)*WS_PITCH + lg*8]);
        int k2 = kc*32 + lg*8;
        int t  = k2 >> 7, c = k2 & 127;
#pragma unroll
        for (int j = 0; j < 4; ++j) {
            int l = (wave*4 + j)*16 + li;
            bf16x8 b2v = *reinterpret_cast<const bf16x8*>(&kT[(l + t)*PC + c]);
#pragma unroll
            for (int mt = 0; mt < 7; ++mt)
                acc2[mt][j] = __builtin_amdgcn_mfma_f32_16x16x32_bf16(
                    a2[mt], b2v, acc2[mt][j], 0,0,0);
        }
        __syncthreads();
    }
    float* psum  = lnbuf;
    float* mrstd = lnbuf + 4*112*2;
#pragma unroll
    for (int mt = 0; mt < 7; ++mt) {
#pragma unroll
        for (int r = 0; r < 4; ++r) {
            float s1 = 0.f, s2 = 0.f;
#pragma unroll
            for (int j = 0; j < 4; ++j) {
                float v = acc2[mt][j][r];
                s1 += v; s2 += v*v;
            }
#pragma unroll
            for (int m = 1; m < 16; m <<= 1) {
                s1 += __shfl_xor(s1, m, 64);
                s2 += __shfl_xor(s2, m, 64);
            }
            if (li == 0) {
                int p = mt*16 + lg*4 + r;
                psum[(wave*112 + p)*2 + 0] = s1;
                psum[(wave*112 + p)*2 + 1] = s2;
            }
        }
    }
    __syncthreads();
    if (tid < 112) {
        float S1 = 0.f, S2 = 0.f;
#pragma unroll
        for (int w2i = 0; w2i < 4; ++w2i) {
            S1 += psum[(w2i*112 + tid)*2 + 0];
            S2 += psum[(w2i*112 + tid)*2 + 1];
        }
        float mean = S1 * (1.0f/HID);
        float var  = S2 * (1.0f/HID) - mean*mean;
        mrstd[tid*2 + 0] = mean;
        mrstd[tid*2 + 1] = rsqrtf(var + 1e-5f);
    }
    __syncthreads();
    float* ob = out + (size_t)b * (NP*HID);
#pragma unroll
    for (int j = 0; j < 4; ++j) {
        int l = (wave*4 + j)*16 + li;
        float g  = gamma[l];
        float be = beta[l];
#pragma unroll
        for (int mt = 0; mt < 7; ++mt) {
#pragma unroll
            for (int r = 0; r < 4; ++r) {
                int p = mt*16 + lg*4 + r;
                if (p < NP) {
                    float mean = mrstd[p*2], rstd = mrstd[p*2 + 1];
                    ob[p*HID + l] = (acc2[mt][j][r] - mean)*rstd*g + be;
                }
            }
        }
    }
}

extern "C" void kernel_launch(void* const* d_in, const int* in_sizes, int n_in,
                              void* d_out, int out_size, void* d_ws, size_t ws_size,
                              hipStream_t stream) {
    const float* f     = (const float*)d_in[0];
    const float* k     = (const float*)d_in[1];
    const float* W_lin = (const float*)d_in[2];
    const float* b_lin = (const float*)d_in[3];
    const float* gamma = (const float*)d_in[4];
    const float* beta  = (const float*)d_in[5];
    float* out = (float*)d_out;

    short* W2f = (short*)d_ws;                                   // 196608 B
    float* b2f = (float*)((char*)d_ws + 196608);                 // 1536 B
    const size_t off_w2 = 198144;
    const int B = in_sizes[0] / (NP*HID);
    const int Mrows = B * NP;
    const size_t need = off_w2 + (size_t)B * 12 * NP * 32 * 2;   // ~78.8 MB @ B=1024

    dyconv_prep<<<48, 256, 0, stream>>>(W_lin, b_lin, W2f, b2f);

    if (ws_size >= need) {
        short* w2 = (short*)((char*)d_ws + off_w2);
        dyconv_gemm1<<<(Mrows + 127)/128, 256, 0, stream>>>(f, W2f, b2f, w2, Mrows);
        dyconv_conv<<<B, 256, 0, stream>>>(k, w2, gamma, beta, out);
    } else {
        dyconv_main<<<B, 256, 0, stream>>>(f, k, W2f, b2f, gamma, beta, out);
    }
}

// Round 17
// 144.200 us; speedup vs baseline: 1.2339x; 1.0363x over previous
//
#include <hip/hip_runtime.h>
#include <hip/hip_bf16.h>

#define HID   256
#define NP    100
#define KSZ   3
#define NPKS  (NP*KSZ)        // 300
#define K2PAD 384             // 3 * 128 (t*128 + c layout)
#define N1T   24              // 384/16 N-tiles of GEMM1
#define PC    104             // kT pitch in bf16 elems (c-dim)
#define KTROWS 258            // l = -1 .. 256
#define WS_PITCH 40
#define WS_ELEMS (112*WS_PITCH)
#define KT_ELEMS_FB (KTROWS*PC + 80)   // fallback kernel's kT (with guard)

using bf16x8 = __attribute__((ext_vector_type(8))) short;
using f32x4  = __attribute__((ext_vector_type(4))) float;

__device__ __forceinline__ short f2bf(float x) {
    __hip_bfloat16 h = __float2bfloat16(x);
    return __builtin_bit_cast(short, h);
}

// ---------- prep: W_lin -> bf16 B-fragment-ordered W2f, permuted bias ----------
__global__ void dyconv_prep(const float* __restrict__ W_lin,
                            const float* __restrict__ b_lin,
                            short* __restrict__ W2f,   // [8 kt][24 nt][64 lane][8] bf16
                            float* __restrict__ b2f) { // [384]
    int gid = blockIdx.x * blockDim.x + threadIdx.x;   // 0..12287
    int lane = gid & 63;
    int ent  = gid >> 6;            // kt*24 + nt
    int kt = ent / N1T;
    int nt = ent % N1T;
    int n  = nt*16 + (lane & 15);   // K2 index of GEMM2 = t*128 + c
    int t  = n >> 7;
    int c  = n & 127;
    int k0 = kt*32 + ((lane >> 4) << 3);
    short vals[8];
#pragma unroll
    for (int j = 0; j < 8; ++j) {
        float v = (c < NP) ? W_lin[(k0 + j) * NPKS + c*KSZ + t] : 0.0f;
        vals[j] = f2bf(v);
    }
    *reinterpret_cast<bf16x8*>(&W2f[(size_t)gid * 8]) =
        *reinterpret_cast<bf16x8*>(vals);
    if (gid < K2PAD) {
        int tt = gid >> 7, cc = gid & 127;
        b2f[gid] = (cc < NP) ? b_lin[cc*KSZ + tt] : 0.0f;
    }
}

// ---------- kernel A v7 (frozen, ~57us): 2-nt DMA chunks, launch_bounds(256,4) ----------
__global__ __launch_bounds__(256, 4)
void dyconv_gemm1(const float* __restrict__ f, const short* __restrict__ W2f,
                  const float* __restrict__ b2f, short* __restrict__ w2, int Mrows) {
    __shared__ short wlds[2][16*512];   // 2 x 16KB: 16 frags (ntl*8+kt) x 1KB
    const int tid = threadIdx.x, wave = tid>>6, lane = tid&63, lg = lane>>4, li = lane&15;
    const int r0 = blockIdx.x * 128;

    bf16x8 a1[2][8];
#pragma unroll
    for (int mi = 0; mi < 2; ++mi) {
        int myr = r0 + (wave*2 + mi)*16 + li; if (myr > Mrows-1) myr = Mrows-1;
        const float* frow = f + (size_t)myr * HID + lg*8;
#pragma unroll
        for (int kt = 0; kt < 8; ++kt) {
            float4 u = *reinterpret_cast<const float4*>(frow + kt*32);
            float4 v = *reinterpret_cast<const float4*>(frow + kt*32 + 4);
            short tmp[8] = {f2bf(u.x),f2bf(u.y),f2bf(u.z),f2bf(u.w),
                            f2bf(v.x),f2bf(v.y),f2bf(v.z),f2bf(v.w)};
            a1[mi][kt] = *reinterpret_cast<bf16x8*>(tmp);
        }
    }

#define STAGE(BUF, C) { _Pragma("unroll") for (int i = 0; i < 4; ++i) { \
        int fi = wave*4 + i; \
        int ntl = fi >> 3, kt = fi & 7; \
        int nt = (C)*2 + ntl; \
        const short* gsrc = &W2f[(((size_t)(kt*N1T + nt))*64 + lane)*8]; \
        __builtin_amdgcn_global_load_lds( \
            (const __attribute__((address_space(1))) unsigned int*)gsrc, \
            (__attribute__((address_space(3))) unsigned int*)&wlds[BUF][fi*512], \
            16, 0, 0); } }

    const int prow0 = lg*4;

    STAGE(0, 0)
    __syncthreads();

#pragma unroll 1
    for (int c = 0; c < 12; ++c) {
        if (c < 11) STAGE((c+1)&1, c+1)

        const short* lbase = wlds[c&1];
        f32x4 acc[2][2];
#pragma unroll
        for (int mi = 0; mi < 2; ++mi)
#pragma unroll
            for (int i = 0; i < 2; ++i) acc[mi][i] = (f32x4){0.f,0.f,0.f,0.f};

#pragma unroll
        for (int ntl = 0; ntl < 2; ++ntl) {
#pragma unroll
            for (int kt = 0; kt < 8; ++kt) {
                bf16x8 bfr = *reinterpret_cast<const bf16x8*>(
                    lbase + (ntl*8 + kt)*512 + lane*8);
                acc[0][ntl] = __builtin_amdgcn_mfma_f32_16x16x32_bf16(
                    a1[0][kt], bfr, acc[0][ntl], 0,0,0);
                acc[1][ntl] = __builtin_amdgcn_mfma_f32_16x16x32_bf16(
                    a1[1][kt], bfr, acc[1][ntl], 0,0,0);
            }
        }

        float bias[2];
#pragma unroll
        for (int ntl = 0; ntl < 2; ++ntl) bias[ntl] = b2f[(c*2 + ntl)*16 + li];

#pragma unroll
        for (int mi = 0; mi < 2; ++mi) {
#pragma unroll
            for (int r = 0; r < 4; ++r) {
                int gr = r0 + (wave*2 + mi)*16 + prow0 + r;
                if (gr < Mrows) {
                    int bb = gr / NP, p = gr % NP;
                    short* wrow = w2 + ((size_t)bb*12*NP + p)*32;
#pragma unroll
                    for (int ntl = 0; ntl < 2; ++ntl) {
                        int nt = c*2 + ntl;
                        wrow[(size_t)(nt>>1)*NP*32 + (nt&1)*16 + li] =
                            f2bf(acc[mi][ntl][r] + bias[ntl]);
                    }
                }
            }
        }
        __syncthreads();
    }
#undef STAGE
}

// ---------- conv v7 helper: one row-pass (NMT m-tiles starting at MTB) ----------
template<int NMT, int MTB>
__device__ __forceinline__ void conv_pass(
    const short* __restrict__ wb, const short* __restrict__ kT,
    float* __restrict__ psumA,
    const float* __restrict__ gamma, const float* __restrict__ beta,
    float* __restrict__ ob, int wave, int lg, int li)
{
    f32x4 acc[NMT][4];
#pragma unroll
    for (int mt = 0; mt < NMT; ++mt)
#pragma unroll
        for (int j = 0; j < 4; ++j) acc[mt][j] = (f32x4){0.f,0.f,0.f,0.f};

    const short* wp[NMT];
#pragma unroll
    for (int mt = 0; mt < NMT; ++mt) {
        int p = (MTB + mt)*16 + li; if (p > NP-1) p = NP-1;
        wp[mt] = wb + (size_t)p*32 + lg*8;
    }

    bf16x8 a2[NMT], a2n[NMT];
#pragma unroll
    for (int mt = 0; mt < NMT; ++mt)
        a2[mt] = *reinterpret_cast<const bf16x8*>(wp[mt]);

#pragma unroll
    for (int kc = 0; kc < 12; ++kc) {
        if (kc < 11) {
#pragma unroll
            for (int mt = 0; mt < NMT; ++mt)
                a2n[mt] = *reinterpret_cast<const bf16x8*>(wp[mt] + (size_t)(kc+1)*NP*32);
        }
        int k2 = kc*32 + lg*8;
        int t  = k2 >> 7, c = k2 & 127;
#pragma unroll
        for (int j = 0; j < 4; ++j) {
            int l = (wave*4 + j)*16 + li;
            bf16x8 b2v = *reinterpret_cast<const bf16x8*>(&kT[(l + t)*PC + c]);
#pragma unroll
            for (int mt = 0; mt < NMT; ++mt)
                acc[mt][j] = __builtin_amdgcn_mfma_f32_16x16x32_bf16(
                    a2[mt], b2v, acc[mt][j], 0,0,0);
        }
#pragma unroll
        for (int mt = 0; mt < NMT; ++mt) a2[mt] = a2n[mt];
    }

    // wave-local partial LN (16-lane shfl) + cross-wave merge via LDS atomics
#pragma unroll
    for (int mt = 0; mt < NMT; ++mt) {
#pragma unroll
        for (int r = 0; r < 4; ++r) {
            float s1 = 0.f, s2 = 0.f;
#pragma unroll
            for (int j = 0; j < 4; ++j) {
                float v = acc[mt][j][r];
                s1 += v; s2 += v*v;
            }
#pragma unroll
            for (int m = 1; m < 16; m <<= 1) {
                s1 += __shfl_xor(s1, m, 64);
                s2 += __shfl_xor(s2, m, 64);
            }
            if (li == 0) {
                int rl = mt*16 + lg*4 + r;
                atomicAdd(&psumA[rl*2 + 0], s1);
                atomicAdd(&psumA[rl*2 + 1], s2);
            }
        }
    }
    __syncthreads();   // psumA complete for this pass

#pragma unroll
    for (int j = 0; j < 4; ++j) {
        int l = (wave*4 + j)*16 + li;
        float g  = gamma[l];
        float be = beta[l];
#pragma unroll
        for (int mt = 0; mt < NMT; ++mt) {
#pragma unroll
            for (int r = 0; r < 4; ++r) {
                int rl = mt*16 + lg*4 + r;
                int p  = MTB*16 + rl;
                if (p < NP) {
                    float S1 = psumA[rl*2], S2 = psumA[rl*2 + 1];
                    float mean = S1 * (1.0f/HID);
                    float rstd = rsqrtf(S2 * (1.0f/HID) - mean*mean + 1e-5f);
                    ob[p*HID + l] = (acc[mt][j][r] - mean)*rstd*g + be;
                }
            }
        }
    }
}

// ---------- kernel B v7: conv + LN, 2 row-passes in one block ----------
// kT staged ONCE; a2n prefetch kept; w2 reads not duplicated. Peak acc 64 AGPR
// -> ~150 unified regs -> 3 waves/SIMD; LDS ~54KB -> 3 blocks/CU (12 waves/CU).
__global__ __launch_bounds__(256, 3)
void dyconv_conv(const float* __restrict__ k, const short* __restrict__ w2,
                 const float* __restrict__ gamma, const float* __restrict__ beta,
                 float* __restrict__ out) {
    __shared__ short kT[KTROWS*PC];    // 53664 B, no guard (max read = row 257 col 103)
    __shared__ float psumA[64*2];      // 512 B LN merge buffer

    const int b = blockIdx.x, tid = threadIdx.x;
    const int wave = tid>>6, lane = tid&63, lg = lane>>4, li = lane&15;

    // zero pad rows 0 (l=-1) and 257 (l=256), c-strip [100,104) rows 1..256
    if (tid < 52) {
        *reinterpret_cast<unsigned int*>(&kT[tid*2]) = 0u;
        *reinterpret_cast<unsigned int*>(&kT[257*PC + tid*2]) = 0u;
    }
    *reinterpret_cast<unsigned long long*>(&kT[(tid+1)*PC + 100]) = 0ull;
    if (tid < 128) psumA[tid] = 0.f;

    // staging: 2 channels packed per b32 write; lanes walk l (stride 52 dwords)
    const float* kb = k + (size_t)b * (NP*HID);
    for (int u = tid; u < (NP/2)*HID; u += 256) {   // 12800 units
        int c2 = u >> 8;              // 0..49
        int l  = u & 255;
        int c  = c2*2;
        float v0 = kb[(size_t)c*HID + l];
        float v1 = kb[(size_t)(c+1)*HID + l];
        unsigned int pk = (unsigned int)(unsigned short)f2bf(v0)
                        | ((unsigned int)(unsigned short)f2bf(v1) << 16);
        *reinterpret_cast<unsigned int*>(&kT[(l+1)*PC + c]) = pk;
    }

    const short* wb = w2 + (size_t)b * 12 * NP * 32;
    float* ob = out + (size_t)b * (NP*HID);

    __syncthreads();   // kT + psumA ready

    conv_pass<4, 0>(wb, kT, psumA, gamma, beta, ob, wave, lg, li);

    __syncthreads();   // all pass-1 psumA reads done
    if (tid < 128) psumA[tid] = 0.f;
    __syncthreads();   // psumA zeroed for pass 2

    conv_pass<3, 4>(wb, kT, psumA, gamma, beta, ob, wave, lg, li);
}

// ---------- fallback fused kernel (proven R1 path) if ws too small ----------
__global__ __launch_bounds__(256)
void dyconv_main(const float* __restrict__ f, const float* __restrict__ k,
                 const short* __restrict__ W2f, const float* __restrict__ b2f,
                 const float* __restrict__ gamma, const float* __restrict__ beta,
                 float* __restrict__ out) {
    __shared__ short kT[KT_ELEMS_FB];
    __shared__ short wS[WS_ELEMS];
    float* lnbuf = reinterpret_cast<float*>(wS);
    const int b = blockIdx.x, tid = threadIdx.x;
    const int wave = tid>>6, lane = tid&63, lg = lane>>4, li = lane&15;
    for (int i = tid; i < KT_ELEMS_FB/8; i += 256)
        reinterpret_cast<int4*>(kT)[i] = make_int4(0,0,0,0);
    __syncthreads();
    const float* kb = k + (size_t)b * (NP*HID);
    for (int idx = tid; idx < NP*HID; idx += 256) {
        int c = idx >> 8, l = idx & 255;
        kT[(l+1)*PC + c] = f2bf(kb[idx]);
    }
    const float* fb = f + (size_t)b * (NP*HID);
    const int nmy = (wave < 3) ? 2 : 1;
    bf16x8 a1[2][8];
#pragma unroll
    for (int mi = 0; mi < 2; ++mi) {
        if (mi < nmy) {
            int mt = wave + 4*mi;
            int p  = mt*16 + li; if (p > NP-1) p = NP-1;
            const float* rowp = fb + (size_t)p * HID + lg*8;
#pragma unroll
            for (int kt = 0; kt < 8; ++kt) {
                float4 u = *reinterpret_cast<const float4*>(rowp + kt*32);
                float4 v = *reinterpret_cast<const float4*>(rowp + kt*32 + 4);
                short tmp[8] = {f2bf(u.x),f2bf(u.y),f2bf(u.z),f2bf(u.w),
                                f2bf(v.x),f2bf(v.y),f2bf(v.z),f2bf(v.w)};
                a1[mi][kt] = *reinterpret_cast<bf16x8*>(tmp);
            }
        }
    }
    f32x4 acc2[7][4];
#pragma unroll
    for (int mt = 0; mt < 7; ++mt)
#pragma unroll
        for (int j = 0; j < 4; ++j) acc2[mt][j] = (f32x4){0.f,0.f,0.f,0.f};
    __syncthreads();
    for (int kc = 0; kc < 12; ++kc) {
        f32x4 acc1[2][2];
#pragma unroll
        for (int mi = 0; mi < 2; ++mi)
#pragma unroll
            for (int n = 0; n < 2; ++n) acc1[mi][n] = (f32x4){0.f,0.f,0.f,0.f};
#pragma unroll
        for (int kt = 0; kt < 8; ++kt) {
            bf16x8 b1[2];
#pragma unroll
            for (int ntl = 0; ntl < 2; ++ntl) {
                int NT = kc*2 + ntl;
                b1[ntl] = *reinterpret_cast<const bf16x8*>(
                    &W2f[(((size_t)kt*N1T + NT)*64 + lane)*8]);
            }
#pragma unroll
            for (int mi = 0; mi < 2; ++mi) {
                if (mi < nmy) {
                    acc1[mi][0] = __builtin_amdgcn_mfma_f32_16x16x32_bf16(
                        a1[mi][kt], b1[0], acc1[mi][0], 0,0,0);
                    acc1[mi][1] = __builtin_amdgcn_mfma_f32_16x16x32_bf16(
                        a1[mi][kt], b1[1], acc1[mi][1], 0,0,0);
                }
            }
        }
#pragma unroll
        for (int mi = 0; mi < 2; ++mi) {
            if (mi < nmy) {
                int mt = wave + 4*mi;
#pragma unroll
                for (int ntl = 0; ntl < 2; ++ntl) {
                    int col  = ntl*16 + li;
                    float bias = b2f[kc*32 + col];
#pragma unroll
                    for (int r = 0; r < 4; ++r) {
                        int row = mt*16 + lg*4 + r;
                        wS[row*WS_PITCH + col] = f2bf(acc1[mi][ntl][r] + bias);
                    }
                }
            }
        }
        __syncthreads();
        bf16x8 a2[7];
#pragma unroll
        for (int mt = 0; mt < 7; ++mt)
            a2[mt] = *reinterpret_cast<const bf16x8*>(&wS[(mt*16 + li)*WS_PITCH + lg*8]);
        int k2 = kc*32 + lg*8;
        int t  = k2 >> 7, c = k2 & 127;
#pragma unroll
        for (int j = 0; j < 4; ++j) {
            int l = (wave*4 + j)*16 + li;
            bf16x8 b2v = *reinterpret_cast<const bf16x8*>(&kT[(l + t)*PC + c]);
#pragma unroll
            for (int mt = 0; mt < 7; ++mt)
                acc2[mt][j] = __builtin_amdgcn_mfma_f32_16x16x32_bf16(
                    a2[mt], b2v, acc2[mt][j], 0,0,0);
        }
        __syncthreads();
    }
    float* psum  = lnbuf;
    float* mrstd = lnbuf + 4*112*2;
#pragma unroll
    for (int mt = 0; mt < 7; ++mt) {
#pragma unroll
        for (int r = 0; r < 4; ++r) {
            float s1 = 0.f, s2 = 0.f;
#pragma unroll
            for (int j = 0; j < 4; ++j) {
                float v = acc2[mt][j][r];
                s1 += v; s2 += v*v;
            }
#pragma unroll
            for (int m = 1; m < 16; m <<= 1) {
                s1 += __shfl_xor(s1, m, 64);
                s2 += __shfl_xor(s2, m, 64);
            }
            if (li == 0) {
                int p = mt*16 + lg*4 + r;
                psum[(wave*112 + p)*2 + 0] = s1;
                psum[(wave*112 + p)*2 + 1] = s2;
            }
        }
    }
    __syncthreads();
    if (tid < 112) {
        float S1 = 0.f, S2 = 0.f;
#pragma unroll
        for (int w2i = 0; w2i < 4; ++w2i) {
            S1 += psum[(w2i*112 + tid)*2 + 0];
            S2 += psum[(w2i*112 + tid)*2 + 1];
        }
        float mean = S1 * (1.0f/HID);
        float var  = S2 * (1.0f/HID) - mean*mean;
        mrstd[tid*2 + 0] = mean;
        mrstd[tid*2 + 1] = rsqrtf(var + 1e-5f);
    }
    __syncthreads();
    float* ob = out + (size_t)b * (NP*HID);
#pragma unroll
    for (int j = 0; j < 4; ++j) {
        int l = (wave*4 + j)*16 + li;
        float g  = gamma[l];
        float be = beta[l];
#pragma unroll
        for (int mt = 0; mt < 7; ++mt) {
#pragma unroll
            for (int r = 0; r < 4; ++r) {
                int p = mt*16 + lg*4 + r;
                if (p < NP) {
                    float mean = mrstd[p*2], rstd = mrstd[p*2 + 1];
                    ob[p*HID + l] = (acc2[mt][j][r] - mean)*rstd*g + be;
                }
            }
        }
    }
}

extern "C" void kernel_launch(void* const* d_in, const int* in_sizes, int n_in,
                              void* d_out, int out_size, void* d_ws, size_t ws_size,
                              hipStream_t stream) {
    const float* f     = (const float*)d_in[0];
    const float* k     = (const float*)d_in[1];
    const float* W_lin = (const float*)d_in[2];
    const float* b_lin = (const float*)d_in[3];
    const float* gamma = (const float*)d_in[4];
    const float* beta  = (const float*)d_in[5];
    float* out = (float*)d_out;

    short* W2f = (short*)d_ws;                                   // 196608 B
    float* b2f = (float*)((char*)d_ws + 196608);                 // 1536 B
    const size_t off_w2 = 198144;
    const int B = in_sizes[0] / (NP*HID);
    const int Mrows = B * NP;
    const size_t need = off_w2 + (size_t)B * 12 * NP * 32 * 2;   // ~78.8 MB @ B=1024

    dyconv_prep<<<48, 256, 0, stream>>>(W_lin, b_lin, W2f, b2f);

    if (ws_size >= need) {
        short* w2 = (short*)((char*)d_ws + off_w2);
        dyconv_gemm1<<<(Mrows + 127)/128, 256, 0, stream>>>(f, W2f, b2f, w2, Mrows);
        dyconv_conv<<<B, 256, 0, stream>>>(k, w2, gamma, beta, out);
    } else {
        dyconv_main<<<B, 256, 0, stream>>>(f, k, W2f, b2f, gamma, beta, out);
    }
}

// Round 18
// 140.869 us; speedup vs baseline: 1.2631x; 1.0236x over previous
//
#include <hip/hip_runtime.h>
#include <hip/hip_bf16.h>

#define HID   256
#define NP    100
#define KSZ   3
#define NPKS  (NP*KSZ)        // 300
#define K2PAD 384             // 3 * 128 (t*128 + c layout)
#define N1T   24              // 384/16 N-tiles of GEMM1
#define PC    104             // kT pitch in bf16 elems (c-dim)
#define KTROWS 258            // l = -1 .. 256
#define WS_PITCH 40
#define WS_ELEMS (112*WS_PITCH)
#define KT_ELEMS_FB (KTROWS*PC + 80)   // fallback kernel's kT (with guard)

using bf16x8 = __attribute__((ext_vector_type(8))) short;
using f32x4  = __attribute__((ext_vector_type(4))) float;

__device__ __forceinline__ short f2bf(float x) {
    __hip_bfloat16 h = __float2bfloat16(x);
    return __builtin_bit_cast(short, h);
}

// ---------- prep: W_lin -> bf16 B-fragment-ordered W2f, permuted bias ----------
__global__ void dyconv_prep(const float* __restrict__ W_lin,
                            const float* __restrict__ b_lin,
                            short* __restrict__ W2f,   // [8 kt][24 nt][64 lane][8] bf16
                            float* __restrict__ b2f) { // [384]
    int gid = blockIdx.x * blockDim.x + threadIdx.x;   // 0..12287
    int lane = gid & 63;
    int ent  = gid >> 6;            // kt*24 + nt
    int kt = ent / N1T;
    int nt = ent % N1T;
    int n  = nt*16 + (lane & 15);   // K2 index of GEMM2 = t*128 + c
    int t  = n >> 7;
    int c  = n & 127;
    int k0 = kt*32 + ((lane >> 4) << 3);
    short vals[8];
#pragma unroll
    for (int j = 0; j < 8; ++j) {
        float v = (c < NP) ? W_lin[(k0 + j) * NPKS + c*KSZ + t] : 0.0f;
        vals[j] = f2bf(v);
    }
    *reinterpret_cast<bf16x8*>(&W2f[(size_t)gid * 8]) =
        *reinterpret_cast<bf16x8*>(vals);
    if (gid < K2PAD) {
        int tt = gid >> 7, cc = gid & 127;
        b2f[gid] = (cc < NP) ? b_lin[cc*KSZ + tt] : 0.0f;
    }
}

// ---------- kernel A v7 (frozen, ~57us): 2-nt DMA chunks, launch_bounds(256,4) ----------
__global__ __launch_bounds__(256, 4)
void dyconv_gemm1(const float* __restrict__ f, const short* __restrict__ W2f,
                  const float* __restrict__ b2f, short* __restrict__ w2, int Mrows) {
    __shared__ short wlds[2][16*512];   // 2 x 16KB: 16 frags (ntl*8+kt) x 1KB
    const int tid = threadIdx.x, wave = tid>>6, lane = tid&63, lg = lane>>4, li = lane&15;
    const int r0 = blockIdx.x * 128;

    bf16x8 a1[2][8];
#pragma unroll
    for (int mi = 0; mi < 2; ++mi) {
        int myr = r0 + (wave*2 + mi)*16 + li; if (myr > Mrows-1) myr = Mrows-1;
        const float* frow = f + (size_t)myr * HID + lg*8;
#pragma unroll
        for (int kt = 0; kt < 8; ++kt) {
            float4 u = *reinterpret_cast<const float4*>(frow + kt*32);
            float4 v = *reinterpret_cast<const float4*>(frow + kt*32 + 4);
            short tmp[8] = {f2bf(u.x),f2bf(u.y),f2bf(u.z),f2bf(u.w),
                            f2bf(v.x),f2bf(v.y),f2bf(v.z),f2bf(v.w)};
            a1[mi][kt] = *reinterpret_cast<bf16x8*>(tmp);
        }
    }

#define STAGE(BUF, C) { _Pragma("unroll") for (int i = 0; i < 4; ++i) { \
        int fi = wave*4 + i; \
        int ntl = fi >> 3, kt = fi & 7; \
        int nt = (C)*2 + ntl; \
        const short* gsrc = &W2f[(((size_t)(kt*N1T + nt))*64 + lane)*8]; \
        __builtin_amdgcn_global_load_lds( \
            (const __attribute__((address_space(1))) unsigned int*)gsrc, \
            (__attribute__((address_space(3))) unsigned int*)&wlds[BUF][fi*512], \
            16, 0, 0); } }

    const int prow0 = lg*4;

    STAGE(0, 0)
    __syncthreads();

#pragma unroll 1
    for (int c = 0; c < 12; ++c) {
        if (c < 11) STAGE((c+1)&1, c+1)

        const short* lbase = wlds[c&1];
        f32x4 acc[2][2];
#pragma unroll
        for (int mi = 0; mi < 2; ++mi)
#pragma unroll
            for (int i = 0; i < 2; ++i) acc[mi][i] = (f32x4){0.f,0.f,0.f,0.f};

#pragma unroll
        for (int ntl = 0; ntl < 2; ++ntl) {
#pragma unroll
            for (int kt = 0; kt < 8; ++kt) {
                bf16x8 bfr = *reinterpret_cast<const bf16x8*>(
                    lbase + (ntl*8 + kt)*512 + lane*8);
                acc[0][ntl] = __builtin_amdgcn_mfma_f32_16x16x32_bf16(
                    a1[0][kt], bfr, acc[0][ntl], 0,0,0);
                acc[1][ntl] = __builtin_amdgcn_mfma_f32_16x16x32_bf16(
                    a1[1][kt], bfr, acc[1][ntl], 0,0,0);
            }
        }

        float bias[2];
#pragma unroll
        for (int ntl = 0; ntl < 2; ++ntl) bias[ntl] = b2f[(c*2 + ntl)*16 + li];

#pragma unroll
        for (int mi = 0; mi < 2; ++mi) {
#pragma unroll
            for (int r = 0; r < 4; ++r) {
                int gr = r0 + (wave*2 + mi)*16 + prow0 + r;
                if (gr < Mrows) {
                    int bb = gr / NP, p = gr % NP;
                    short* wrow = w2 + ((size_t)bb*12*NP + p)*32;
#pragma unroll
                    for (int ntl = 0; ntl < 2; ++ntl) {
                        int nt = c*2 + ntl;
                        wrow[(size_t)(nt>>1)*NP*32 + (nt&1)*16 + li] =
                            f2bf(acc[mi][ntl][r] + bias[ntl]);
                    }
                }
            }
        }
        __syncthreads();
    }
#undef STAGE
}

// ---------- conv helper: one row-pass (NMT m-tiles starting at MTB) ----------
template<int NMT, int MTB>
__device__ __forceinline__ void conv_pass(
    const short* __restrict__ wb, const short* __restrict__ kT,
    float* __restrict__ psumA,
    const float* __restrict__ gamma, const float* __restrict__ beta,
    float* __restrict__ ob, int wave, int lg, int li)
{
    f32x4 acc[NMT][4];
#pragma unroll
    for (int mt = 0; mt < NMT; ++mt)
#pragma unroll
        for (int j = 0; j < 4; ++j) acc[mt][j] = (f32x4){0.f,0.f,0.f,0.f};

    const short* wp[NMT];
#pragma unroll
    for (int mt = 0; mt < NMT; ++mt) {
        int p = (MTB + mt)*16 + li; if (p > NP-1) p = NP-1;
        wp[mt] = wb + (size_t)p*32 + lg*8;
    }

    bf16x8 a2[NMT], a2n[NMT];
#pragma unroll
    for (int mt = 0; mt < NMT; ++mt)
        a2[mt] = *reinterpret_cast<const bf16x8*>(wp[mt]);

#pragma unroll
    for (int kc = 0; kc < 12; ++kc) {
        if (kc < 11) {
#pragma unroll
            for (int mt = 0; mt < NMT; ++mt)
                a2n[mt] = *reinterpret_cast<const bf16x8*>(wp[mt] + (size_t)(kc+1)*NP*32);
        }
        int k2 = kc*32 + lg*8;
        int t  = k2 >> 7, c = k2 & 127;
#pragma unroll
        for (int j = 0; j < 4; ++j) {
            int l = (wave*4 + j)*16 + li;
            bf16x8 b2v = *reinterpret_cast<const bf16x8*>(&kT[(l + t)*PC + c]);
#pragma unroll
            for (int mt = 0; mt < NMT; ++mt)
                acc[mt][j] = __builtin_amdgcn_mfma_f32_16x16x32_bf16(
                    a2[mt], b2v, acc[mt][j], 0,0,0);
        }
#pragma unroll
        for (int mt = 0; mt < NMT; ++mt) a2[mt] = a2n[mt];
    }

    // wave-local partial LN (16-lane shfl) + cross-wave merge via LDS atomics
#pragma unroll
    for (int mt = 0; mt < NMT; ++mt) {
#pragma unroll
        for (int r = 0; r < 4; ++r) {
            float s1 = 0.f, s2 = 0.f;
#pragma unroll
            for (int j = 0; j < 4; ++j) {
                float v = acc[mt][j][r];
                s1 += v; s2 += v*v;
            }
#pragma unroll
            for (int m = 1; m < 16; m <<= 1) {
                s1 += __shfl_xor(s1, m, 64);
                s2 += __shfl_xor(s2, m, 64);
            }
            if (li == 0) {
                int rl = mt*16 + lg*4 + r;
                atomicAdd(&psumA[rl*2 + 0], s1);
                atomicAdd(&psumA[rl*2 + 1], s2);
            }
        }
    }
    __syncthreads();   // psumA complete for this pass

#pragma unroll
    for (int j = 0; j < 4; ++j) {
        int l = (wave*4 + j)*16 + li;
        float g  = gamma[l];
        float be = beta[l];
#pragma unroll
        for (int mt = 0; mt < NMT; ++mt) {
#pragma unroll
            for (int r = 0; r < 4; ++r) {
                int rl = mt*16 + lg*4 + r;
                int p  = MTB*16 + rl;
                if (p < NP) {
                    float S1 = psumA[rl*2], S2 = psumA[rl*2 + 1];
                    float mean = S1 * (1.0f/HID);
                    float rstd = rsqrtf(S2 * (1.0f/HID) - mean*mean + 1e-5f);
                    ob[p*HID + l] = (acc[mt][j][r] - mean)*rstd*g + be;
                }
            }
        }
    }
}

// ---------- kernel B v8: conv + LN, 2 row-passes; staging loop unrolled 5x ----------
// Only change vs v7: #pragma unroll 5 on the staging loop -> 10 global loads in
// flight per thread (was ~2), amortizing HBM latency across the 50 iterations.
__global__ __launch_bounds__(256, 3)
void dyconv_conv(const float* __restrict__ k, const short* __restrict__ w2,
                 const float* __restrict__ gamma, const float* __restrict__ beta,
                 float* __restrict__ out) {
    __shared__ short kT[KTROWS*PC];    // 53664 B, no guard (max read = row 257 col 103)
    __shared__ float psumA[64*2];      // 512 B LN merge buffer

    const int b = blockIdx.x, tid = threadIdx.x;
    const int wave = tid>>6, lane = tid&63, lg = lane>>4, li = lane&15;

    // zero pad rows 0 (l=-1) and 257 (l=256), c-strip [100,104) rows 1..256
    if (tid < 52) {
        *reinterpret_cast<unsigned int*>(&kT[tid*2]) = 0u;
        *reinterpret_cast<unsigned int*>(&kT[257*PC + tid*2]) = 0u;
    }
    *reinterpret_cast<unsigned long long*>(&kT[(tid+1)*PC + 100]) = 0ull;
    if (tid < 128) psumA[tid] = 0.f;

    // staging: 2 channels packed per b32 write; lanes walk l (stride 52 dwords)
    // unroll 5 -> 10 independent global loads in flight per thread
    const float* kb = k + (size_t)b * (NP*HID);
#pragma unroll 5
    for (int u = tid; u < (NP/2)*HID; u += 256) {   // 12800 units, 50 iters
        int c2 = u >> 8;              // 0..49
        int l  = u & 255;
        int c  = c2*2;
        float v0 = kb[(size_t)c*HID + l];
        float v1 = kb[(size_t)(c+1)*HID + l];
        unsigned int pk = (unsigned int)(unsigned short)f2bf(v0)
                        | ((unsigned int)(unsigned short)f2bf(v1) << 16);
        *reinterpret_cast<unsigned int*>(&kT[(l+1)*PC + c]) = pk;
    }

    const short* wb = w2 + (size_t)b * 12 * NP * 32;
    float* ob = out + (size_t)b * (NP*HID);

    __syncthreads();   // kT + psumA ready

    conv_pass<4, 0>(wb, kT, psumA, gamma, beta, ob, wave, lg, li);

    __syncthreads();   // all pass-1 psumA reads done
    if (tid < 128) psumA[tid] = 0.f;
    __syncthreads();   // psumA zeroed for pass 2

    conv_pass<3, 4>(wb, kT, psumA, gamma, beta, ob, wave, lg, li);
}

// ---------- fallback fused kernel (proven R1 path) if ws too small ----------
__global__ __launch_bounds__(256)
void dyconv_main(const float* __restrict__ f, const float* __restrict__ k,
                 const short* __restrict__ W2f, const float* __restrict__ b2f,
                 const float* __restrict__ gamma, const float* __restrict__ beta,
                 float* __restrict__ out) {
    __shared__ short kT[KT_ELEMS_FB];
    __shared__ short wS[WS_ELEMS];
    float* lnbuf = reinterpret_cast<float*>(wS);
    const int b = blockIdx.x, tid = threadIdx.x;
    const int wave = tid>>6, lane = tid&63, lg = lane>>4, li = lane&15;
    for (int i = tid; i < KT_ELEMS_FB/8; i += 256)
        reinterpret_cast<int4*>(kT)[i] = make_int4(0,0,0,0);
    __syncthreads();
    const float* kb = k + (size_t)b * (NP*HID);
    for (int idx = tid; idx < NP*HID; idx += 256) {
        int c = idx >> 8, l = idx & 255;
        kT[(l+1)*PC + c] = f2bf(kb[idx]);
    }
    const float* fb = f + (size_t)b * (NP*HID);
    const int nmy = (wave < 3) ? 2 : 1;
    bf16x8 a1[2][8];
#pragma unroll
    for (int mi = 0; mi < 2; ++mi) {
        if (mi < nmy) {
            int mt = wave + 4*mi;
            int p  = mt*16 + li; if (p > NP-1) p = NP-1;
            const float* rowp = fb + (size_t)p * HID + lg*8;
#pragma unroll
            for (int kt = 0; kt < 8; ++kt) {
                float4 u = *reinterpret_cast<const float4*>(rowp + kt*32);
                float4 v = *reinterpret_cast<const float4*>(rowp + kt*32 + 4);
                short tmp[8] = {f2bf(u.x),f2bf(u.y),f2bf(u.z),f2bf(u.w),
                                f2bf(v.x),f2bf(v.y),f2bf(v.z),f2bf(v.w)};
                a1[mi][kt] = *reinterpret_cast<bf16x8*>(tmp);
            }
        }
    }
    f32x4 acc2[7][4];
#pragma unroll
    for (int mt = 0; mt < 7; ++mt)
#pragma unroll
        for (int j = 0; j < 4; ++j) acc2[mt][j] = (f32x4){0.f,0.f,0.f,0.f};
    __syncthreads();
    for (int kc = 0; kc < 12; ++kc) {
        f32x4 acc1[2][2];
#pragma unroll
        for (int mi = 0; mi < 2; ++mi)
#pragma unroll
            for (int n = 0; n < 2; ++n) acc1[mi][n] = (f32x4){0.f,0.f,0.f,0.f};
#pragma unroll
        for (int kt = 0; kt < 8; ++kt) {
            bf16x8 b1[2];
#pragma unroll
            for (int ntl = 0; ntl < 2; ++ntl) {
                int NT = kc*2 + ntl;
                b1[ntl] = *reinterpret_cast<const bf16x8*>(
                    &W2f[(((size_t)kt*N1T + NT)*64 + lane)*8]);
            }
#pragma unroll
            for (int mi = 0; mi < 2; ++mi) {
                if (mi < nmy) {
                    acc1[mi][0] = __builtin_amdgcn_mfma_f32_16x16x32_bf16(
                        a1[mi][kt], b1[0], acc1[mi][0], 0,0,0);
                    acc1[mi][1] = __builtin_amdgcn_mfma_f32_16x16x32_bf16(
                        a1[mi][kt], b1[1], acc1[mi][1], 0,0,0);
                }
            }
        }
#pragma unroll
        for (int mi = 0; mi < 2; ++mi) {
            if (mi < nmy) {
                int mt = wave + 4*mi;
#pragma unroll
                for (int ntl = 0; ntl < 2; ++ntl) {
                    int col  = ntl*16 + li;
                    float bias = b2f[kc*32 + col];
#pragma unroll
                    for (int r = 0; r < 4; ++r) {
                        int row = mt*16 + lg*4 + r;
                        wS[row*WS_PITCH + col] = f2bf(acc1[mi][ntl][r] + bias);
                    }
                }
            }
        }
        __syncthreads();
        bf16x8 a2[7];
#pragma unroll
        for (int mt = 0; mt < 7; ++mt)
            a2[mt] = *reinterpret_cast<const bf16x8*>(&wS[(mt*16 + li)*WS_PITCH + lg*8]);
        int k2 = kc*32 + lg*8;
        int t  = k2 >> 7, c = k2 & 127;
#pragma unroll
        for (int j = 0; j < 4; ++j) {
            int l = (wave*4 + j)*16 + li;
            bf16x8 b2v = *reinterpret_cast<const bf16x8*>(&kT[(l + t)*PC + c]);
#pragma unroll
            for (int mt = 0; mt < 7; ++mt)
                acc2[mt][j] = __builtin_amdgcn_mfma_f32_16x16x32_bf16(
                    a2[mt], b2v, acc2[mt][j], 0,0,0);
        }
        __syncthreads();
    }
    float* psum  = lnbuf;
    float* mrstd = lnbuf + 4*112*2;
#pragma unroll
    for (int mt = 0; mt < 7; ++mt) {
#pragma unroll
        for (int r = 0; r < 4; ++r) {
            float s1 = 0.f, s2 = 0.f;
#pragma unroll
            for (int j = 0; j < 4; ++j) {
                float v = acc2[mt][j][r];
                s1 += v; s2 += v*v;
            }
#pragma unroll
            for (int m = 1; m < 16; m <<= 1) {
                s1 += __shfl_xor(s1, m, 64);
                s2 += __shfl_xor(s2, m, 64);
            }
            if (li == 0) {
                int p = mt*16 + lg*4 + r;
                psum[(wave*112 + p)*2 + 0] = s1;
                psum[(wave*112 + p)*2 + 1] = s2;
            }
        }
    }
    __syncthreads();
    if (tid < 112) {
        float S1 = 0.f, S2 = 0.f;
#pragma unroll
        for (int w2i = 0; w2i < 4; ++w2i) {
            S1 += psum[(w2i*112 + tid)*2 + 0];
            S2 += psum[(w2i*112 + tid)*2 + 1];
        }
        float mean = S1 * (1.0f/HID);
        float var  = S2 * (1.0f/HID) - mean*mean;
        mrstd[tid*2 + 0] = mean;
        mrstd[tid*2 + 1] = rsqrtf(var + 1e-5f);
    }
    __syncthreads();
    float* ob = out + (size_t)b * (NP*HID);
#pragma unroll
    for (int j = 0; j < 4; ++j) {
        int l = (wave*4 + j)*16 + li;
        float g  = gamma[l];
        float be = beta[l];
#pragma unroll
        for (int mt = 0; mt < 7; ++mt) {
#pragma unroll
            for (int r = 0; r < 4; ++r) {
                int p = mt*16 + lg*4 + r;
                if (p < NP) {
                    float mean = mrstd[p*2], rstd = mrstd[p*2 + 1];
                    ob[p*HID + l] = (acc2[mt][j][r] - mean)*rstd*g + be;
                }
            }
        }
    }
}

extern "C" void kernel_launch(void* const* d_in, const int* in_sizes, int n_in,
                              void* d_out, int out_size, void* d_ws, size_t ws_size,
                              hipStream_t stream) {
    const float* f     = (const float*)d_in[0];
    const float* k     = (const float*)d_in[1];
    const float* W_lin = (const float*)d_in[2];
    const float* b_lin = (const float*)d_in[3];
    const float* gamma = (const float*)d_in[4];
    const float* beta  = (const float*)d_in[5];
    float* out = (float*)d_out;

    short* W2f = (short*)d_ws;                                   // 196608 B
    float* b2f = (float*)((char*)d_ws + 196608);                 // 1536 B
    const size_t off_w2 = 198144;
    const int B = in_sizes[0] / (NP*HID);
    const int Mrows = B * NP;
    const size_t need = off_w2 + (size_t)B * 12 * NP * 32 * 2;   // ~78.8 MB @ B=1024

    dyconv_prep<<<48, 256, 0, stream>>>(W_lin, b_lin, W2f, b2f);

    if (ws_size >= need) {
        short* w2 = (short*)((char*)d_ws + off_w2);
        dyconv_gemm1<<<(Mrows + 127)/128, 256, 0, stream>>>(f, W2f, b2f, w2, Mrows);
        dyconv_conv<<<B, 256, 0, stream>>>(k, w2, gamma, beta, out);
    } else {
        dyconv_main<<<B, 256, 0, stream>>>(f, k, W2f, b2f, gamma, beta, out);
    }
}